// Round 1
// baseline (724.110 us; speedup 1.0000x reference)
//
#include <hip/hip_runtime.h>
#include <stdint.h>

// WASLL R5: occupancy-reshaped 3-pass bucketed permutation.
// R4 evidence: p2 at 82us with Occ=37%, VALUBusy 8%, HBM 21% -> latency-bound
// at 2 blocks/CU (70KB LDS). R5 keeps the algorithm and geometry (8192-pin
// buckets, 16384-slot j-buckets, identical run lengths) but:
//   - 1024-thread blocks everywhere: 2 resident blocks = 32 waves/CU (100%)
//     p1 72KB, p2 68KB, p3 64KB -- all fit 2 blocks in 160KB LDS
//   - wave-0 scan fused with the global cursor atomicAdd; hist[] is reused to
//     hold (gbase - scn) so the output index is hist[b] + k (one less barrier,
//     one less LDS array, one less full-block phase per round)
//   - cur2 double-buffered per dim -> reinit launch removed
//   - __launch_bounds__(1024, 8) pins VGPR <= 64 for 8 waves/SIMD

#define PINB_SHIFT 13
#define PINB_SIZE  (1 << PINB_SHIFT)      // 8192 pins/bucket = 32KB window
#define MAX_PINB   1024
#define JB_SHIFT   14
#define JB_SIZE    (1 << JB_SHIFT)        // 16384 slots/j-bucket (4096 nets)
#define MAX_JB     512
#define P1_CHUNK   8192                   // entries per P1 block
#define P2_CHUNK   4096                   // entries per P2 round
#define NTHR       1024

__device__ __forceinline__ float wa4(float a, float b, float c, float d, float ig) {
    float ea = __expf(a * ig), eb = __expf(b * ig);
    float ec = __expf(c * ig), ed = __expf(d * ig);
    float na = __expf(-a * ig), nb = __expf(-b * ig);
    float nc = __expf(-c * ig), nd = __expf(-d * ig);
    float s_ep  = ea + eb + ec + ed;
    float s_xep = a * ea + b * eb + c * ec + d * ed;
    float s_en  = na + nb + nc + nd;
    float s_xen = a * na + b * nb + c * nc + d * nd;
    return s_xep / s_ep - s_xen / s_en;
}

__global__ void init_kernel(unsigned* __restrict__ cur1, int n_pinb,
                            unsigned* __restrict__ cur2, int n_jb,
                            float* __restrict__ out) {
    int t = threadIdx.x;
    if (t == 0) out[0] = 0.0f;
    for (int i = t; i < n_pinb; i += blockDim.x) cur1[i] = (unsigned)i << PINB_SHIFT;
    for (int i = t; i < 2 * n_jb; i += blockDim.x) {
        int j = (i < n_jb) ? i : (i - n_jb);
        cur2[i] = (unsigned)j << JB_SHIFT;
    }
}

// ---------------- P1: partition (pin, j) by 8192-pin bucket ----------------
__global__ __launch_bounds__(NTHR, 8) void p1_partition(
    const int4* __restrict__ fnp4, int NP, int n_pinb,
    uint2* __restrict__ ent1, unsigned* __restrict__ cur1)
{
    __shared__ uint2    staged[P1_CHUNK];        // 64KB
    __shared__ unsigned hist[MAX_PINB];          // 4KB (count, then gbase-scn)
    __shared__ unsigned scn[MAX_PINB];           // 4KB
    const int base  = blockIdx.x * P1_CHUNK;
    const int valid = min(P1_CHUNK, NP - base);  // multiple of 4 (NP%4==0)
    const int t = threadIdx.x;

    if (t < MAX_PINB) hist[t] = 0;
    __syncthreads();

    // 8 pins/thread via int4; rank pass builds histogram
    unsigned pin[8], rnk[8];
    #pragma unroll
    for (int m4 = 0; m4 < 2; ++m4) {
        int k4 = t + NTHR * m4;
        int kk = 4 * k4;
        int4 v = make_int4(0, 0, 0, 0);
        if (kk < valid) v = fnp4[(base >> 2) + k4];
        pin[4*m4+0] = (unsigned)v.x; pin[4*m4+1] = (unsigned)v.y;
        pin[4*m4+2] = (unsigned)v.z; pin[4*m4+3] = (unsigned)v.w;
    }
    #pragma unroll
    for (int m4 = 0; m4 < 2; ++m4)
        #pragma unroll
        for (int c = 0; c < 4; ++c) {
            int kk = 4 * (t + NTHR * m4) + c;
            rnk[4*m4+c] = 0;
            if (kk < valid)
                rnk[4*m4+c] = atomicAdd(&hist[pin[4*m4+c] >> PINB_SHIFT], 1u);
        }
    __syncthreads();

    // wave-0: shuffle scan over MAX_PINB buckets (16/lane), fused cursor
    // atomic; hist[b] <- gbase - scn[b] (output delta)
    if (t < 64) {
        unsigned v[16], s = 0;
        #pragma unroll
        for (int i = 0; i < 16; ++i) { v[i] = hist[t * 16 + i]; s += v[i]; }
        unsigned e = s;
        #pragma unroll
        for (int off = 1; off < 64; off <<= 1) {
            unsigned u = __shfl_up(e, off, 64);
            if (t >= off) e += u;
        }
        e -= s;  // exclusive base for this lane's chunk
        #pragma unroll
        for (int i = 0; i < 16; ++i) {
            scn[t * 16 + i] = e;
            unsigned g = v[i] ? atomicAdd(&cur1[t * 16 + i], v[i]) : 0u;
            hist[t * 16 + i] = g - e;   // delta; unsigned wrap is fine
            e += v[i];
        }
    }
    __syncthreads();

    #pragma unroll
    for (int m4 = 0; m4 < 2; ++m4)
        #pragma unroll
        for (int c = 0; c < 4; ++c) {
            int kk = 4 * (t + NTHR * m4) + c;
            if (kk < valid) {
                unsigned p = pin[4*m4+c];
                staged[scn[p >> PINB_SHIFT] + rnk[4*m4+c]] =
                    make_uint2(p, (unsigned)(base + kk));
            }
        }
    __syncthreads();

    for (int k = t; k < valid; k += NTHR) {      // coalesced bucket-run writes
        uint2 e = staged[k];
        unsigned b = e.x >> PINB_SHIFT;
        ent1[hist[b] + (unsigned)k] = e;         // gbase + (k - scn[b])
    }
}

// ------- P2: LDS-window gather + repartition by 16384-slot j-bucket -------
__global__ __launch_bounds__(NTHR, 8) void p2_gather(
    const uint2* __restrict__ ent1, const float2* __restrict__ pos2,
    const int* __restrict__ slrx_p, const int* __restrict__ slry_p,
    int d, int NP, int n_jb,
    uint2* __restrict__ ent2, unsigned* __restrict__ cur2)
{
    const int slr = (d == 0) ? slrx_p[0] : slry_p[0];
    if (slr <= 1) return;                        // dim off: whole pipeline idle

    __shared__ float    win[PINB_SIZE];          // 32KB component window
    __shared__ uint2    staged[P2_CHUNK];        // 32KB
    __shared__ unsigned hist[MAX_JB], scn[MAX_JB];  // 4KB
    const int b       = blockIdx.x;
    const int pbase   = b << PINB_SHIFT;
    const int count_b = min(PINB_SIZE, NP - pbase);
    const int t = threadIdx.x;

    for (int i = t; i < count_b; i += NTHR) {    // coalesced window load
        float2 p = pos2[pbase + i];
        win[i] = d ? p.y : p.x;
    }

    #pragma unroll
    for (int r = 0; r < PINB_SIZE / P2_CHUNK; ++r) {   // 2 rounds
        const int cbase = r * P2_CHUNK;
        const int valid = min(P2_CHUNK, count_b - cbase);
        __syncthreads();                         // window ready / prior staged read done
        if (t < MAX_JB) hist[t] = 0;
        __syncthreads();

        uint2 e[4]; unsigned rnk[4]; float yv[4];
        #pragma unroll
        for (int m = 0; m < 4; ++m) {            // coalesced entry loads
            int k = t + NTHR * m;
            e[m] = make_uint2(0u, 0u);
            if (k < valid) e[m] = ent1[pbase + cbase + k];
        }
        #pragma unroll
        for (int m = 0; m < 4; ++m) {            // LDS gathers
            int k = t + NTHR * m;
            yv[m] = (k < valid) ? win[e[m].x - (unsigned)pbase] : 0.0f;
        }
        #pragma unroll
        for (int m = 0; m < 4; ++m) {            // rank + histogram in one pass
            int k = t + NTHR * m;
            rnk[m] = 0;
            if (k < valid) rnk[m] = atomicAdd(&hist[e[m].y >> JB_SHIFT], 1u);
        }
        __syncthreads();

        // wave-0 scan (8 buckets/lane) fused with cursor atomic
        if (t < 64) {
            unsigned v[8], s = 0;
            #pragma unroll
            for (int i = 0; i < 8; ++i) { v[i] = hist[t * 8 + i]; s += v[i]; }
            unsigned ex = s;
            #pragma unroll
            for (int off = 1; off < 64; off <<= 1) {
                unsigned u = __shfl_up(ex, off, 64);
                if (t >= off) ex += u;
            }
            ex -= s;
            #pragma unroll
            for (int i = 0; i < 8; ++i) {
                scn[t * 8 + i] = ex;
                unsigned g = v[i] ? atomicAdd(&cur2[t * 8 + i], v[i]) : 0u;
                hist[t * 8 + i] = g - ex;
                ex += v[i];
            }
        }
        __syncthreads();

        #pragma unroll
        for (int m = 0; m < 4; ++m) {
            int k = t + NTHR * m;
            if (k < valid)
                staged[scn[e[m].y >> JB_SHIFT] + rnk[m]] =
                    make_uint2(e[m].y, __float_as_uint(yv[m]));
        }
        __syncthreads();

        for (int k = t; k < valid; k += NTHR) {  // coalesced bucket-run writes
            uint2 s2 = staged[k];
            unsigned jb = s2.x >> JB_SHIFT;
            ent2[hist[jb] + (unsigned)k] = s2;
        }
    }
}

// ------------- P3: LDS slot tile, per-net wa4, global reduce -------------
__global__ __launch_bounds__(NTHR, 8) void p3_compute(
    const uint2* __restrict__ ent2, const float* __restrict__ wts,
    const float* __restrict__ ig_p,
    const int* __restrict__ slrx_p, const int* __restrict__ slry_p,
    int d, int NP, float* __restrict__ out)
{
    const int slr = (d == 0) ? slrx_p[0] : slry_p[0];
    if (slr <= 1) return;

    __shared__ float ytmp[JB_SIZE];              // 64KB
    const int jb     = blockIdx.x;
    const int base_j = jb << JB_SHIFT;
    const int nslots = min(JB_SIZE, NP - base_j);  // multiple of 4
    const int t = threadIdx.x;
    const float ig = ig_p[0];

    for (int k = t; k < nslots; k += NTHR) {     // coalesced read, LDS scatter
        uint2 e = ent2[base_j + k];
        ytmp[e.x & (JB_SIZE - 1)] = __uint_as_float(e.y);
    }
    __syncthreads();

    float val = 0.0f;
    const int nnets = nslots >> 2, bnet = base_j >> 2;
    const float4* y4 = (const float4*)ytmp;
    for (int i = t; i < nnets; i += NTHR) {
        float4 p = y4[i];                        // ds_read_b128
        val += wts[bnet + i] * wa4(p.x, p.y, p.z, p.w, ig);
    }

    #pragma unroll
    for (int off = 32; off > 0; off >>= 1) val += __shfl_down(val, off, 64);
    __syncthreads();
    if ((t & 63) == 0) ytmp[t >> 6] = val;
    __syncthreads();
    if (t == 0) {
        float s = 0.0f;
        #pragma unroll
        for (int w = 0; w < 16; ++w) s += ytmp[w];
        atomicAdd(out, s);
    }
}

// ---------------- fallback: proven R1 gather kernel ----------------
__global__ __launch_bounds__(256) void wasll_fallback(
    const float2* __restrict__ pos, const int4* __restrict__ fnp4,
    const float* __restrict__ net_weights, const float* __restrict__ inv_gamma_p,
    const int* __restrict__ slrx_p, const int* __restrict__ slry_p,
    float* __restrict__ out, int num_nets)
{
    const float ig = inv_gamma_p[0];
    const float dx = (slrx_p[0] > 1) ? 1.0f : 0.0f;
    const float dy = (slry_p[0] > 1) ? 1.0f : 0.0f;
    int net = blockIdx.x * blockDim.x + threadIdx.x;
    float val = 0.0f;
    if (net < num_nets) {
        int4 idx = fnp4[net];
        float2 p0 = pos[idx.x], p1 = pos[idx.y], p2 = pos[idx.z], p3 = pos[idx.w];
        val = net_weights[net] * (dx * wa4(p0.x, p1.x, p2.x, p3.x, ig)
                                + dy * wa4(p0.y, p1.y, p2.y, p3.y, ig));
    }
    #pragma unroll
    for (int off = 32; off > 0; off >>= 1) val += __shfl_down(val, off, 64);
    __shared__ float smem[4];
    if ((threadIdx.x & 63) == 0) smem[threadIdx.x >> 6] = val;
    __syncthreads();
    if (threadIdx.x == 0)
        atomicAdd(out, smem[0] + smem[1] + smem[2] + smem[3]);
}

__global__ void zero_out_kernel(float* __restrict__ out) { out[0] = 0.0f; }

extern "C" void kernel_launch(void* const* d_in, const int* in_sizes, int n_in,
                              void* d_out, int out_size, void* d_ws, size_t ws_size,
                              hipStream_t stream) {
    const float* posf        = (const float*)d_in[0];
    const int*   fnp         = (const int*)d_in[1];
    const float* net_weights = (const float*)d_in[4];
    const float* inv_gamma   = (const float*)d_in[7];
    const int*   slrx        = (const int*)d_in[8];
    const int*   slry        = (const int*)d_in[9];
    float*       out         = (float*)d_out;
    const int    N  = in_sizes[4];
    const int    NP = in_sizes[1];

    const int n_pinb = (NP + PINB_SIZE - 1) >> PINB_SHIFT;
    const int n_jb   = (NP + JB_SIZE - 1) >> JB_SHIFT;

    size_t off = 0;
    auto carve = [&](size_t bytes) { size_t o = off; off += (bytes + 255) & ~size_t(255); return o; };
    size_t o_ent1 = carve((size_t)n_pinb * PINB_SIZE * sizeof(uint2));
    size_t o_ent2 = carve((size_t)n_jb * JB_SIZE * sizeof(uint2));
    size_t o_cur1 = carve((size_t)n_pinb * sizeof(unsigned));
    size_t o_cur2 = carve((size_t)2 * n_jb * sizeof(unsigned));  // double-buffered per dim

    const bool ok = (NP == 4 * N) && (NP % 4 == 0) &&
                    (n_pinb <= MAX_PINB) && (n_jb <= MAX_JB) && (off <= ws_size);
    if (!ok) {
        hipLaunchKernelGGL(zero_out_kernel, dim3(1), dim3(1), 0, stream, out);
        const int block = 256, grid = (N + block - 1) / block;
        hipLaunchKernelGGL(wasll_fallback, dim3(grid), dim3(block), 0, stream,
                           (const float2*)posf, (const int4*)fnp, net_weights,
                           inv_gamma, slrx, slry, out, N);
        return;
    }

    char* ws = (char*)d_ws;
    uint2*    ent1 = (uint2*)(ws + o_ent1);
    uint2*    ent2 = (uint2*)(ws + o_ent2);
    unsigned* cur1 = (unsigned*)(ws + o_cur1);
    unsigned* cur2 = (unsigned*)(ws + o_cur2);

    hipLaunchKernelGGL(init_kernel, dim3(1), dim3(1024), 0, stream,
                       cur1, n_pinb, cur2, n_jb, out);

    const int g1 = (NP + P1_CHUNK - 1) / P1_CHUNK;
    hipLaunchKernelGGL(p1_partition, dim3(g1), dim3(NTHR), 0, stream,
                       (const int4*)fnp, NP, n_pinb, ent1, cur1);

    // d = 0 (x): early-exits when num_slrX <= 1
    hipLaunchKernelGGL(p2_gather, dim3(n_pinb), dim3(NTHR), 0, stream,
                       ent1, (const float2*)posf, slrx, slry, 0, NP, n_jb, ent2, cur2);
    hipLaunchKernelGGL(p3_compute, dim3(n_jb), dim3(NTHR), 0, stream,
                       ent2, net_weights, inv_gamma, slrx, slry, 0, NP, out);

    // d = 1 (y): second cur2 buffer, no reinit launch needed
    hipLaunchKernelGGL(p2_gather, dim3(n_pinb), dim3(NTHR), 0, stream,
                       ent1, (const float2*)posf, slrx, slry, 1, NP, n_jb, ent2, cur2 + n_jb);
    hipLaunchKernelGGL(p3_compute, dim3(n_jb), dim3(NTHR), 0, stream,
                       ent2, net_weights, inv_gamma, slrx, slry, 1, NP, out);
}

// Round 2
// 634.322 us; speedup vs baseline: 1.1416x; 1.1416x over previous
//
#include <hip/hip_runtime.h>
#include <stdint.h>

// WASLL R6: single-round p2 with LDS window/staged aliasing.
// R5 post-mortem: __launch_bounds__(1024,8) capped VGPR at 64 -> pin[]/rnk[]
// spilled to scratch (VGPR_Count=32, WRITE_SIZE 112MB vs 66MB needed, VALU 1.5%).
// Occupancy rose 37->80% but scratch latency dominated: -2.6x. Lesson: the
// 512-thread/2-block shape is register-bound, not occupancy-tunable.
// R6 reverts to 512 threads everywhere and removes machinery instead:
//   - p2 processes the full 8192-entry bucket in ONE round: entry loads all
//     issued up front (latency exposed once), win (32KB, dead after gather)
//     aliased with staged (64KB) -> 68KB total, same 2 blocks/CU as R4, but
//     4 barriers/block instead of 8 and 1 wave-0 scan instead of 2.
//     Output run length doubles to 16 entries = 128B coalesced runs.
//   - fused scan+cursor-atomic kept (R5 correctness-verified), saves a barrier
//     and the gbase[] array in p1 and p2.
//   - cur2 double-buffered per dim -> no reinit launch.

#define PINB_SHIFT 13
#define PINB_SIZE  (1 << PINB_SHIFT)      // 8192 pins/bucket = 32KB window
#define MAX_PINB   1024
#define JB_SHIFT   14
#define JB_SIZE    (1 << JB_SHIFT)        // 16384 slots/j-bucket (4096 nets)
#define MAX_JB     512
#define P1_CHUNK   8192                   // entries per P1 block
#define NTHR       512

__device__ __forceinline__ float wa4(float a, float b, float c, float d, float ig) {
    float ea = __expf(a * ig), eb = __expf(b * ig);
    float ec = __expf(c * ig), ed = __expf(d * ig);
    float na = __expf(-a * ig), nb = __expf(-b * ig);
    float nc = __expf(-c * ig), nd = __expf(-d * ig);
    float s_ep  = ea + eb + ec + ed;
    float s_xep = a * ea + b * eb + c * ec + d * ed;
    float s_en  = na + nb + nc + nd;
    float s_xen = a * na + b * nb + c * nc + d * nd;
    return s_xep / s_ep - s_xen / s_en;
}

__global__ void init_kernel(unsigned* __restrict__ cur1, int n_pinb,
                            unsigned* __restrict__ cur2, int n_jb,
                            float* __restrict__ out) {
    int t = threadIdx.x;
    if (t == 0) out[0] = 0.0f;
    for (int i = t; i < n_pinb; i += blockDim.x) cur1[i] = (unsigned)i << PINB_SHIFT;
    for (int i = t; i < 2 * n_jb; i += blockDim.x) {
        int j = (i < n_jb) ? i : (i - n_jb);
        cur2[i] = (unsigned)j << JB_SHIFT;
    }
}

// ---------------- P1: partition (pin, j) by 8192-pin bucket ----------------
__global__ __launch_bounds__(NTHR) void p1_partition(
    const int4* __restrict__ fnp4, int NP, int n_pinb,
    uint2* __restrict__ ent1, unsigned* __restrict__ cur1)
{
    __shared__ uint2    staged[P1_CHUNK];        // 64KB
    __shared__ unsigned hist[MAX_PINB];          // 4KB (count, then gbase-scn)
    __shared__ unsigned scn[MAX_PINB];           // 4KB
    const int base  = blockIdx.x * P1_CHUNK;
    const int valid = min(P1_CHUNK, NP - base);  // multiple of 4 (NP%4==0)
    const int t = threadIdx.x;

    for (int b = t; b < MAX_PINB; b += NTHR) hist[b] = 0;
    __syncthreads();

    // 16 pins/thread via int4; rank pass builds histogram
    unsigned pin[16], rnk[16];
    #pragma unroll
    for (int m4 = 0; m4 < 4; ++m4) {
        int k4 = t + NTHR * m4;
        int kk = 4 * k4;
        int4 v = make_int4(0, 0, 0, 0);
        if (kk < valid) v = fnp4[(base >> 2) + k4];
        pin[4*m4+0] = (unsigned)v.x; pin[4*m4+1] = (unsigned)v.y;
        pin[4*m4+2] = (unsigned)v.z; pin[4*m4+3] = (unsigned)v.w;
    }
    #pragma unroll
    for (int m4 = 0; m4 < 4; ++m4)
        #pragma unroll
        for (int c = 0; c < 4; ++c) {
            int kk = 4 * (t + NTHR * m4) + c;
            rnk[4*m4+c] = 0;
            if (kk < valid)
                rnk[4*m4+c] = atomicAdd(&hist[pin[4*m4+c] >> PINB_SHIFT], 1u);
        }
    __syncthreads();

    // wave-0 shuffle scan (16 buckets/lane) fused with cursor atomicAdd;
    // hist[b] <- gbase - scn[b] so output index is hist[b] + k.
    if (t < 64) {
        unsigned v[16], s = 0;
        #pragma unroll
        for (int i = 0; i < 16; ++i) { v[i] = hist[t * 16 + i]; s += v[i]; }
        unsigned e = s;
        #pragma unroll
        for (int off = 1; off < 64; off <<= 1) {
            unsigned u = __shfl_up(e, off, 64);
            if (t >= off) e += u;
        }
        e -= s;  // exclusive base for this lane's chunk
        #pragma unroll
        for (int i = 0; i < 16; ++i) {
            scn[t * 16 + i] = e;
            unsigned g = v[i] ? atomicAdd(&cur1[t * 16 + i], v[i]) : 0u;
            hist[t * 16 + i] = g - e;   // delta; unsigned wrap is fine
            e += v[i];
        }
    }
    __syncthreads();

    #pragma unroll
    for (int m4 = 0; m4 < 4; ++m4)
        #pragma unroll
        for (int c = 0; c < 4; ++c) {
            int kk = 4 * (t + NTHR * m4) + c;
            if (kk < valid) {
                unsigned p = pin[4*m4+c];
                staged[scn[p >> PINB_SHIFT] + rnk[4*m4+c]] =
                    make_uint2(p, (unsigned)(base + kk));
            }
        }
    __syncthreads();

    for (int k = t; k < valid; k += NTHR) {      // coalesced bucket-run writes
        uint2 e = staged[k];
        unsigned b = e.x >> PINB_SHIFT;
        ent1[hist[b] + (unsigned)k] = e;         // gbase + (k - scn[b])
    }
}

// ------- P2: LDS-window gather + repartition by 16384-slot j-bucket -------
// Single round over the whole 8192-entry bucket; win and staged alias.
__global__ __launch_bounds__(NTHR) void p2_gather(
    const uint2* __restrict__ ent1, const float2* __restrict__ pos2,
    const int* __restrict__ slrx_p, const int* __restrict__ slry_p,
    int d, int NP, int n_jb,
    uint2* __restrict__ ent2, unsigned* __restrict__ cur2)
{
    const int slr = (d == 0) ? slrx_p[0] : slry_p[0];
    if (slr <= 1) return;                        // dim off: whole pipeline idle

    // union: bytes [0,32K) = win (dead after gather), [0,64K) = staged
    __shared__ __align__(16) char smem[PINB_SIZE * sizeof(uint2) + 2 * MAX_JB * 4];
    float*    win    = (float*)smem;                                  // 32KB
    uint2*    staged = (uint2*)smem;                                  // 64KB
    unsigned* hist   = (unsigned*)(smem + PINB_SIZE * sizeof(uint2));          // 2KB
    unsigned* scn    = (unsigned*)(smem + PINB_SIZE * sizeof(uint2) + MAX_JB * 4); // 2KB

    const int pbase = blockIdx.x << PINB_SHIFT;
    const int valid = min(PINB_SIZE, NP - pbase);
    const int t = threadIdx.x;

    // 1) issue all entry loads up front (16/thread, latency exposed once)
    uint2 e[16];
    #pragma unroll
    for (int m = 0; m < 16; ++m) {
        int k = t + NTHR * m;
        e[m] = make_uint2(0u, 0u);
        if (k < valid) e[m] = ent1[pbase + k];
    }
    // 2) coalesced window load (overlaps entry loads) + hist zero
    for (int i = t; i < valid; i += NTHR) {
        float2 p = pos2[pbase + i];
        win[i] = d ? p.y : p.x;
    }
    if (t < MAX_JB) hist[t] = 0;                 // NTHR == MAX_JB
    __syncthreads();

    // 3) LDS gather + rank/histogram
    float yv[16]; unsigned rnk[16];
    #pragma unroll
    for (int m = 0; m < 16; ++m) {
        int k = t + NTHR * m;
        yv[m] = (k < valid) ? win[e[m].x & (PINB_SIZE - 1)] : 0.0f;
    }
    #pragma unroll
    for (int m = 0; m < 16; ++m) {
        int k = t + NTHR * m;
        rnk[m] = 0;
        if (k < valid) rnk[m] = atomicAdd(&hist[e[m].y >> JB_SHIFT], 1u);
    }
    __syncthreads();                             // all win reads + hist atomics done

    // 4) wave-0 scan (8 buckets/lane) fused with cursor atomic
    if (t < 64) {
        unsigned v[8], s = 0;
        #pragma unroll
        for (int i = 0; i < 8; ++i) { v[i] = hist[t * 8 + i]; s += v[i]; }
        unsigned ex = s;
        #pragma unroll
        for (int off = 1; off < 64; off <<= 1) {
            unsigned u = __shfl_up(ex, off, 64);
            if (t >= off) ex += u;
        }
        ex -= s;
        #pragma unroll
        for (int i = 0; i < 8; ++i) {
            scn[t * 8 + i] = ex;
            unsigned g = v[i] ? atomicAdd(&cur2[t * 8 + i], v[i]) : 0u;
            hist[t * 8 + i] = g - ex;
            ex += v[i];
        }
    }
    __syncthreads();

    // 5) stage into the union (overwrites win -- all reads completed above)
    #pragma unroll
    for (int m = 0; m < 16; ++m) {
        int k = t + NTHR * m;
        if (k < valid)
            staged[scn[e[m].y >> JB_SHIFT] + rnk[m]] =
                make_uint2(e[m].y, __float_as_uint(yv[m]));
    }
    __syncthreads();

    // 6) coalesced bucket-run writes (~16-entry = 128B runs)
    for (int k = t; k < valid; k += NTHR) {
        uint2 s2 = staged[k];
        unsigned jb = s2.x >> JB_SHIFT;
        ent2[hist[jb] + (unsigned)k] = s2;
    }
}

// ------------- P3: LDS slot tile, per-net wa4, global reduce -------------
__global__ __launch_bounds__(NTHR) void p3_compute(
    const uint2* __restrict__ ent2, const float* __restrict__ wts,
    const float* __restrict__ ig_p,
    const int* __restrict__ slrx_p, const int* __restrict__ slry_p,
    int d, int NP, float* __restrict__ out)
{
    const int slr = (d == 0) ? slrx_p[0] : slry_p[0];
    if (slr <= 1) return;

    __shared__ float ytmp[JB_SIZE];              // 64KB
    const int jb     = blockIdx.x;
    const int base_j = jb << JB_SHIFT;
    const int nslots = min(JB_SIZE, NP - base_j);  // multiple of 4
    const int t = threadIdx.x;
    const float ig = ig_p[0];

    for (int k = t; k < nslots; k += NTHR) {     // coalesced read, LDS scatter
        uint2 e = ent2[base_j + k];
        ytmp[e.x & (JB_SIZE - 1)] = __uint_as_float(e.y);
    }
    __syncthreads();

    float val = 0.0f;
    const int nnets = nslots >> 2, bnet = base_j >> 2;
    const float4* y4 = (const float4*)ytmp;
    for (int i = t; i < nnets; i += NTHR) {
        float4 p = y4[i];                        // ds_read_b128
        val += wts[bnet + i] * wa4(p.x, p.y, p.z, p.w, ig);
    }

    #pragma unroll
    for (int off = 32; off > 0; off >>= 1) val += __shfl_down(val, off, 64);
    __syncthreads();
    if ((t & 63) == 0) ytmp[t >> 6] = val;
    __syncthreads();
    if (t == 0) {
        float s = 0.0f;
        #pragma unroll
        for (int w = 0; w < NTHR / 64; ++w) s += ytmp[w];
        atomicAdd(out, s);
    }
}

// ---------------- fallback: proven R1 gather kernel ----------------
__global__ __launch_bounds__(256) void wasll_fallback(
    const float2* __restrict__ pos, const int4* __restrict__ fnp4,
    const float* __restrict__ net_weights, const float* __restrict__ inv_gamma_p,
    const int* __restrict__ slrx_p, const int* __restrict__ slry_p,
    float* __restrict__ out, int num_nets)
{
    const float ig = inv_gamma_p[0];
    const float dx = (slrx_p[0] > 1) ? 1.0f : 0.0f;
    const float dy = (slry_p[0] > 1) ? 1.0f : 0.0f;
    int net = blockIdx.x * blockDim.x + threadIdx.x;
    float val = 0.0f;
    if (net < num_nets) {
        int4 idx = fnp4[net];
        float2 p0 = pos[idx.x], p1 = pos[idx.y], p2 = pos[idx.z], p3 = pos[idx.w];
        val = net_weights[net] * (dx * wa4(p0.x, p1.x, p2.x, p3.x, ig)
                                + dy * wa4(p0.y, p1.y, p2.y, p3.y, ig));
    }
    #pragma unroll
    for (int off = 32; off > 0; off >>= 1) val += __shfl_down(val, off, 64);
    __shared__ float smem[4];
    if ((threadIdx.x & 63) == 0) smem[threadIdx.x >> 6] = val;
    __syncthreads();
    if (threadIdx.x == 0)
        atomicAdd(out, smem[0] + smem[1] + smem[2] + smem[3]);
}

__global__ void zero_out_kernel(float* __restrict__ out) { out[0] = 0.0f; }

extern "C" void kernel_launch(void* const* d_in, const int* in_sizes, int n_in,
                              void* d_out, int out_size, void* d_ws, size_t ws_size,
                              hipStream_t stream) {
    const float* posf        = (const float*)d_in[0];
    const int*   fnp         = (const int*)d_in[1];
    const float* net_weights = (const float*)d_in[4];
    const float* inv_gamma   = (const float*)d_in[7];
    const int*   slrx        = (const int*)d_in[8];
    const int*   slry        = (const int*)d_in[9];
    float*       out         = (float*)d_out;
    const int    N  = in_sizes[4];
    const int    NP = in_sizes[1];

    const int n_pinb = (NP + PINB_SIZE - 1) >> PINB_SHIFT;
    const int n_jb   = (NP + JB_SIZE - 1) >> JB_SHIFT;

    size_t off = 0;
    auto carve = [&](size_t bytes) { size_t o = off; off += (bytes + 255) & ~size_t(255); return o; };
    size_t o_ent1 = carve((size_t)n_pinb * PINB_SIZE * sizeof(uint2));
    size_t o_ent2 = carve((size_t)n_jb * JB_SIZE * sizeof(uint2));
    size_t o_cur1 = carve((size_t)n_pinb * sizeof(unsigned));
    size_t o_cur2 = carve((size_t)2 * n_jb * sizeof(unsigned));  // double-buffered per dim

    const bool ok = (NP == 4 * N) && (NP % 4 == 0) &&
                    (n_pinb <= MAX_PINB) && (n_jb <= MAX_JB) && (off <= ws_size);
    if (!ok) {
        hipLaunchKernelGGL(zero_out_kernel, dim3(1), dim3(1), 0, stream, out);
        const int block = 256, grid = (N + block - 1) / block;
        hipLaunchKernelGGL(wasll_fallback, dim3(grid), dim3(block), 0, stream,
                           (const float2*)posf, (const int4*)fnp, net_weights,
                           inv_gamma, slrx, slry, out, N);
        return;
    }

    char* ws = (char*)d_ws;
    uint2*    ent1 = (uint2*)(ws + o_ent1);
    uint2*    ent2 = (uint2*)(ws + o_ent2);
    unsigned* cur1 = (unsigned*)(ws + o_cur1);
    unsigned* cur2 = (unsigned*)(ws + o_cur2);

    hipLaunchKernelGGL(init_kernel, dim3(1), dim3(1024), 0, stream,
                       cur1, n_pinb, cur2, n_jb, out);

    const int g1 = (NP + P1_CHUNK - 1) / P1_CHUNK;
    hipLaunchKernelGGL(p1_partition, dim3(g1), dim3(NTHR), 0, stream,
                       (const int4*)fnp, NP, n_pinb, ent1, cur1);

    // d = 0 (x): early-exits when num_slrX <= 1
    hipLaunchKernelGGL(p2_gather, dim3(n_pinb), dim3(NTHR), 0, stream,
                       ent1, (const float2*)posf, slrx, slry, 0, NP, n_jb, ent2, cur2);
    hipLaunchKernelGGL(p3_compute, dim3(n_jb), dim3(NTHR), 0, stream,
                       ent2, net_weights, inv_gamma, slrx, slry, 0, NP, out);

    // d = 1 (y): second cur2 buffer, no reinit launch needed
    hipLaunchKernelGGL(p2_gather, dim3(n_pinb), dim3(NTHR), 0, stream,
                       ent1, (const float2*)posf, slrx, slry, 1, NP, n_jb, ent2, cur2 + n_jb);
    hipLaunchKernelGGL(p3_compute, dim3(n_jb), dim3(NTHR), 0, stream,
                       ent2, net_weights, inv_gamma, slrx, slry, 1, NP, out);
}

// Round 3
// 632.499 us; speedup vs baseline: 1.1448x; 1.0029x over previous
//
#include <hip/hip_runtime.h>
#include <stdint.h>

// WASLL R7: R6 structure + register policy fix.
// R5/R6 post-mortem: hipcc's DEFAULT allocation targets ~8 waves/EU (<=64
// VGPR) and spills rather than allocate more -- both 16-item kernels got
// VGPR_Count=52 + ~45MB scratch writes (WRITE_SIZE 109-112MB vs 67MB useful),
// VALUBusy ~1.5%, 310us. LDS already caps residency at 2 blocks/CU = 4
// waves/EU, where 128 VGPRs are free. Fix: __launch_bounds__(512, 4) on all
// heavy kernels. Also split the fused-scan cursor atomics into issue-loop +
// consume-loop so they pipeline (16 in flight, not 16 serialized).
// Structure unchanged from R6 (correctness-verified): single-round p2 with
// win/staged LDS aliasing, fused scan+cursor-atomic, double-buffered cur2.

#define PINB_SHIFT 13
#define PINB_SIZE  (1 << PINB_SHIFT)      // 8192 pins/bucket = 32KB window
#define MAX_PINB   1024
#define JB_SHIFT   14
#define JB_SIZE    (1 << JB_SHIFT)        // 16384 slots/j-bucket (4096 nets)
#define MAX_JB     512
#define P1_CHUNK   8192                   // entries per P1 block
#define NTHR       512

__device__ __forceinline__ float wa4(float a, float b, float c, float d, float ig) {
    float ea = __expf(a * ig), eb = __expf(b * ig);
    float ec = __expf(c * ig), ed = __expf(d * ig);
    float na = __expf(-a * ig), nb = __expf(-b * ig);
    float nc = __expf(-c * ig), nd = __expf(-d * ig);
    float s_ep  = ea + eb + ec + ed;
    float s_xep = a * ea + b * eb + c * ec + d * ed;
    float s_en  = na + nb + nc + nd;
    float s_xen = a * na + b * nb + c * nc + d * nd;
    return s_xep / s_ep - s_xen / s_en;
}

__global__ void init_kernel(unsigned* __restrict__ cur1, int n_pinb,
                            unsigned* __restrict__ cur2, int n_jb,
                            float* __restrict__ out) {
    int t = threadIdx.x;
    if (t == 0) out[0] = 0.0f;
    for (int i = t; i < n_pinb; i += blockDim.x) cur1[i] = (unsigned)i << PINB_SHIFT;
    for (int i = t; i < 2 * n_jb; i += blockDim.x) {
        int j = (i < n_jb) ? i : (i - n_jb);
        cur2[i] = (unsigned)j << JB_SHIFT;
    }
}

// ---------------- P1: partition (pin, j) by 8192-pin bucket ----------------
__global__ __launch_bounds__(NTHR, 4) void p1_partition(
    const int4* __restrict__ fnp4, int NP, int n_pinb,
    uint2* __restrict__ ent1, unsigned* __restrict__ cur1)
{
    __shared__ uint2    staged[P1_CHUNK];        // 64KB
    __shared__ unsigned hist[MAX_PINB];          // 4KB (count, then gbase-scn)
    __shared__ unsigned scn[MAX_PINB];           // 4KB
    const int base  = blockIdx.x * P1_CHUNK;
    const int valid = min(P1_CHUNK, NP - base);  // multiple of 4 (NP%4==0)
    const int t = threadIdx.x;

    for (int b = t; b < MAX_PINB; b += NTHR) hist[b] = 0;
    __syncthreads();

    // 16 pins/thread via int4; rank pass builds histogram
    unsigned pin[16], rnk[16];
    #pragma unroll
    for (int m4 = 0; m4 < 4; ++m4) {
        int k4 = t + NTHR * m4;
        int kk = 4 * k4;
        int4 v = make_int4(0, 0, 0, 0);
        if (kk < valid) v = fnp4[(base >> 2) + k4];
        pin[4*m4+0] = (unsigned)v.x; pin[4*m4+1] = (unsigned)v.y;
        pin[4*m4+2] = (unsigned)v.z; pin[4*m4+3] = (unsigned)v.w;
    }
    #pragma unroll
    for (int m4 = 0; m4 < 4; ++m4)
        #pragma unroll
        for (int c = 0; c < 4; ++c) {
            int kk = 4 * (t + NTHR * m4) + c;
            rnk[4*m4+c] = 0;
            if (kk < valid)
                rnk[4*m4+c] = atomicAdd(&hist[pin[4*m4+c] >> PINB_SHIFT], 1u);
        }
    __syncthreads();

    // wave-0 shuffle scan (16 buckets/lane) fused with cursor atomicAdd;
    // hist[b] <- gbase - scn[b] so output index is hist[b] + k.
    if (t < 64) {
        unsigned v[16], g[16], s = 0;
        #pragma unroll
        for (int i = 0; i < 16; ++i) { v[i] = hist[t * 16 + i]; s += v[i]; }
        unsigned e = s;
        #pragma unroll
        for (int off = 1; off < 64; off <<= 1) {
            unsigned u = __shfl_up(e, off, 64);
            if (t >= off) e += u;
        }
        e -= s;  // exclusive base for this lane's chunk
        #pragma unroll
        for (int i = 0; i < 16; ++i)             // issue all atomics (pipelined)
            g[i] = v[i] ? atomicAdd(&cur1[t * 16 + i], v[i]) : 0u;
        #pragma unroll
        for (int i = 0; i < 16; ++i) {
            scn[t * 16 + i] = e;
            hist[t * 16 + i] = g[i] - e;         // delta; unsigned wrap is fine
            e += v[i];
        }
    }
    __syncthreads();

    #pragma unroll
    for (int m4 = 0; m4 < 4; ++m4)
        #pragma unroll
        for (int c = 0; c < 4; ++c) {
            int kk = 4 * (t + NTHR * m4) + c;
            if (kk < valid) {
                unsigned p = pin[4*m4+c];
                staged[scn[p >> PINB_SHIFT] + rnk[4*m4+c]] =
                    make_uint2(p, (unsigned)(base + kk));
            }
        }
    __syncthreads();

    for (int k = t; k < valid; k += NTHR) {      // coalesced bucket-run writes
        uint2 e = staged[k];
        unsigned b = e.x >> PINB_SHIFT;
        ent1[hist[b] + (unsigned)k] = e;         // gbase + (k - scn[b])
    }
}

// ------- P2: LDS-window gather + repartition by 16384-slot j-bucket -------
// Single round over the whole 8192-entry bucket; win and staged alias.
__global__ __launch_bounds__(NTHR, 4) void p2_gather(
    const uint2* __restrict__ ent1, const float2* __restrict__ pos2,
    const int* __restrict__ slrx_p, const int* __restrict__ slry_p,
    int d, int NP, int n_jb,
    uint2* __restrict__ ent2, unsigned* __restrict__ cur2)
{
    const int slr = (d == 0) ? slrx_p[0] : slry_p[0];
    if (slr <= 1) return;                        // dim off: whole pipeline idle

    // union: bytes [0,32K) = win (dead after gather), [0,64K) = staged
    __shared__ __align__(16) char smem[PINB_SIZE * sizeof(uint2) + 2 * MAX_JB * 4];
    float*    win    = (float*)smem;                                  // 32KB
    uint2*    staged = (uint2*)smem;                                  // 64KB
    unsigned* hist   = (unsigned*)(smem + PINB_SIZE * sizeof(uint2));          // 2KB
    unsigned* scn    = (unsigned*)(smem + PINB_SIZE * sizeof(uint2) + MAX_JB * 4); // 2KB

    const int pbase = blockIdx.x << PINB_SHIFT;
    const int valid = min(PINB_SIZE, NP - pbase);
    const int t = threadIdx.x;

    // 1) issue all entry loads up front (16/thread, latency exposed once)
    uint2 e[16];
    #pragma unroll
    for (int m = 0; m < 16; ++m) {
        int k = t + NTHR * m;
        e[m] = make_uint2(0u, 0u);
        if (k < valid) e[m] = ent1[pbase + k];
    }
    // 2) coalesced window load (overlaps entry loads) + hist zero
    for (int i = t; i < valid; i += NTHR) {
        float2 p = pos2[pbase + i];
        win[i] = d ? p.y : p.x;
    }
    if (t < MAX_JB) hist[t] = 0;                 // NTHR == MAX_JB
    __syncthreads();

    // 3) LDS gather + rank/histogram
    float yv[16]; unsigned rnk[16];
    #pragma unroll
    for (int m = 0; m < 16; ++m) {
        int k = t + NTHR * m;
        yv[m] = (k < valid) ? win[e[m].x & (PINB_SIZE - 1)] : 0.0f;
    }
    #pragma unroll
    for (int m = 0; m < 16; ++m) {
        int k = t + NTHR * m;
        rnk[m] = 0;
        if (k < valid) rnk[m] = atomicAdd(&hist[e[m].y >> JB_SHIFT], 1u);
    }
    __syncthreads();                             // all win reads + hist atomics done

    // 4) wave-0 scan (8 buckets/lane) fused with cursor atomic
    if (t < 64) {
        unsigned v[8], g[8], s = 0;
        #pragma unroll
        for (int i = 0; i < 8; ++i) { v[i] = hist[t * 8 + i]; s += v[i]; }
        unsigned ex = s;
        #pragma unroll
        for (int off = 1; off < 64; off <<= 1) {
            unsigned u = __shfl_up(ex, off, 64);
            if (t >= off) ex += u;
        }
        ex -= s;
        #pragma unroll
        for (int i = 0; i < 8; ++i)              // issue all atomics (pipelined)
            g[i] = v[i] ? atomicAdd(&cur2[t * 8 + i], v[i]) : 0u;
        #pragma unroll
        for (int i = 0; i < 8; ++i) {
            scn[t * 8 + i] = ex;
            hist[t * 8 + i] = g[i] - ex;
            ex += v[i];
        }
    }
    __syncthreads();

    // 5) stage into the union (overwrites win -- all reads completed above)
    #pragma unroll
    for (int m = 0; m < 16; ++m) {
        int k = t + NTHR * m;
        if (k < valid)
            staged[scn[e[m].y >> JB_SHIFT] + rnk[m]] =
                make_uint2(e[m].y, __float_as_uint(yv[m]));
    }
    __syncthreads();

    // 6) coalesced bucket-run writes (~16-entry = 128B runs)
    for (int k = t; k < valid; k += NTHR) {
        uint2 s2 = staged[k];
        unsigned jb = s2.x >> JB_SHIFT;
        ent2[hist[jb] + (unsigned)k] = s2;
    }
}

// ------------- P3: LDS slot tile, per-net wa4, global reduce -------------
__global__ __launch_bounds__(NTHR, 4) void p3_compute(
    const uint2* __restrict__ ent2, const float* __restrict__ wts,
    const float* __restrict__ ig_p,
    const int* __restrict__ slrx_p, const int* __restrict__ slry_p,
    int d, int NP, float* __restrict__ out)
{
    const int slr = (d == 0) ? slrx_p[0] : slry_p[0];
    if (slr <= 1) return;

    __shared__ float ytmp[JB_SIZE];              // 64KB
    const int jb     = blockIdx.x;
    const int base_j = jb << JB_SHIFT;
    const int nslots = min(JB_SIZE, NP - base_j);  // multiple of 4
    const int t = threadIdx.x;
    const float ig = ig_p[0];

    for (int k = t; k < nslots; k += NTHR) {     // coalesced read, LDS scatter
        uint2 e = ent2[base_j + k];
        ytmp[e.x & (JB_SIZE - 1)] = __uint_as_float(e.y);
    }
    __syncthreads();

    float val = 0.0f;
    const int nnets = nslots >> 2, bnet = base_j >> 2;
    const float4* y4 = (const float4*)ytmp;
    for (int i = t; i < nnets; i += NTHR) {
        float4 p = y4[i];                        // ds_read_b128
        val += wts[bnet + i] * wa4(p.x, p.y, p.z, p.w, ig);
    }

    #pragma unroll
    for (int off = 32; off > 0; off >>= 1) val += __shfl_down(val, off, 64);
    __syncthreads();
    if ((t & 63) == 0) ytmp[t >> 6] = val;
    __syncthreads();
    if (t == 0) {
        float s = 0.0f;
        #pragma unroll
        for (int w = 0; w < NTHR / 64; ++w) s += ytmp[w];
        atomicAdd(out, s);
    }
}

// ---------------- fallback: proven R1 gather kernel ----------------
__global__ __launch_bounds__(256) void wasll_fallback(
    const float2* __restrict__ pos, const int4* __restrict__ fnp4,
    const float* __restrict__ net_weights, const float* __restrict__ inv_gamma_p,
    const int* __restrict__ slrx_p, const int* __restrict__ slry_p,
    float* __restrict__ out, int num_nets)
{
    const float ig = inv_gamma_p[0];
    const float dx = (slrx_p[0] > 1) ? 1.0f : 0.0f;
    const float dy = (slry_p[0] > 1) ? 1.0f : 0.0f;
    int net = blockIdx.x * blockDim.x + threadIdx.x;
    float val = 0.0f;
    if (net < num_nets) {
        int4 idx = fnp4[net];
        float2 p0 = pos[idx.x], p1 = pos[idx.y], p2 = pos[idx.z], p3 = pos[idx.w];
        val = net_weights[net] * (dx * wa4(p0.x, p1.x, p2.x, p3.x, ig)
                                + dy * wa4(p0.y, p1.y, p2.y, p3.y, ig));
    }
    #pragma unroll
    for (int off = 32; off > 0; off >>= 1) val += __shfl_down(val, off, 64);
    __shared__ float smem[4];
    if ((threadIdx.x & 63) == 0) smem[threadIdx.x >> 6] = val;
    __syncthreads();
    if (threadIdx.x == 0)
        atomicAdd(out, smem[0] + smem[1] + smem[2] + smem[3]);
}

__global__ void zero_out_kernel(float* __restrict__ out) { out[0] = 0.0f; }

extern "C" void kernel_launch(void* const* d_in, const int* in_sizes, int n_in,
                              void* d_out, int out_size, void* d_ws, size_t ws_size,
                              hipStream_t stream) {
    const float* posf        = (const float*)d_in[0];
    const int*   fnp         = (const int*)d_in[1];
    const float* net_weights = (const float*)d_in[4];
    const float* inv_gamma   = (const float*)d_in[7];
    const int*   slrx        = (const int*)d_in[8];
    const int*   slry        = (const int*)d_in[9];
    float*       out         = (float*)d_out;
    const int    N  = in_sizes[4];
    const int    NP = in_sizes[1];

    const int n_pinb = (NP + PINB_SIZE - 1) >> PINB_SHIFT;
    const int n_jb   = (NP + JB_SIZE - 1) >> JB_SHIFT;

    size_t off = 0;
    auto carve = [&](size_t bytes) { size_t o = off; off += (bytes + 255) & ~size_t(255); return o; };
    size_t o_ent1 = carve((size_t)n_pinb * PINB_SIZE * sizeof(uint2));
    size_t o_ent2 = carve((size_t)n_jb * JB_SIZE * sizeof(uint2));
    size_t o_cur1 = carve((size_t)n_pinb * sizeof(unsigned));
    size_t o_cur2 = carve((size_t)2 * n_jb * sizeof(unsigned));  // double-buffered per dim

    const bool ok = (NP == 4 * N) && (NP % 4 == 0) &&
                    (n_pinb <= MAX_PINB) && (n_jb <= MAX_JB) && (off <= ws_size);
    if (!ok) {
        hipLaunchKernelGGL(zero_out_kernel, dim3(1), dim3(1), 0, stream, out);
        const int block = 256, grid = (N + block - 1) / block;
        hipLaunchKernelGGL(wasll_fallback, dim3(grid), dim3(block), 0, stream,
                           (const float2*)posf, (const int4*)fnp, net_weights,
                           inv_gamma, slrx, slry, out, N);
        return;
    }

    char* ws = (char*)d_ws;
    uint2*    ent1 = (uint2*)(ws + o_ent1);
    uint2*    ent2 = (uint2*)(ws + o_ent2);
    unsigned* cur1 = (unsigned*)(ws + o_cur1);
    unsigned* cur2 = (unsigned*)(ws + o_cur2);

    hipLaunchKernelGGL(init_kernel, dim3(1), dim3(1024), 0, stream,
                       cur1, n_pinb, cur2, n_jb, out);

    const int g1 = (NP + P1_CHUNK - 1) / P1_CHUNK;
    hipLaunchKernelGGL(p1_partition, dim3(g1), dim3(NTHR), 0, stream,
                       (const int4*)fnp, NP, n_pinb, ent1, cur1);

    // d = 0 (x): early-exits when num_slrX <= 1
    hipLaunchKernelGGL(p2_gather, dim3(n_pinb), dim3(NTHR), 0, stream,
                       ent1, (const float2*)posf, slrx, slry, 0, NP, n_jb, ent2, cur2);
    hipLaunchKernelGGL(p3_compute, dim3(n_jb), dim3(NTHR), 0, stream,
                       ent2, net_weights, inv_gamma, slrx, slry, 0, NP, out);

    // d = 1 (y): second cur2 buffer, no reinit launch needed
    hipLaunchKernelGGL(p2_gather, dim3(n_pinb), dim3(NTHR), 0, stream,
                       ent1, (const float2*)posf, slrx, slry, 1, NP, n_jb, ent2, cur2 + n_jb);
    hipLaunchKernelGGL(p3_compute, dim3(n_jb), dim3(NTHR), 0, stream,
                       ent2, net_weights, inv_gamma, slrx, slry, 1, NP, out);
}

// Round 4
// 275.638 us; speedup vs baseline: 2.6270x; 2.2947x over previous
//
#include <hip/hip_runtime.h>
#include <stdint.h>

// WASLL R8: excise the fused wave-0 cursor atomics (the R5/R6/R7 poison).
// Evidence: p1 was 310us across THREE different shapes (1024t/VGPR32,
// 512t/VGPR52, 512t/VGPR56+launch_bounds) -- constant runtime despite shape
// changes = shared memory-system serialization, not spill. The one shared
// delta vs R4's proven <=82us p1: the fused scan's per-lane conditional
// atomics (16 divergent device-scope atomicAdds serialized per wave-0 lane,
// each a full contention-queue round-trip, on the block critical path).
// R4's all-thread pass (one atomic per thread, overlapped across 16 waves)
// is the proven-fast primitive.
// R8 = R4's p1/p3 verbatim + R6's single-round p2 (win/staged aliasing,
// 16-deep load pipeline -- structurally better than R4's 2-round p2) with
// the scan/atomic phases reverted to R4 style. cur2 double-buffer kept.

#define PINB_SHIFT 13
#define PINB_SIZE  (1 << PINB_SHIFT)      // 8192 pins/bucket = 32KB window
#define MAX_PINB   1024
#define JB_SHIFT   14
#define JB_SIZE    (1 << JB_SHIFT)        // 16384 slots/j-bucket (4096 nets)
#define MAX_JB     512
#define P1_CHUNK   8192                   // entries per P1 block
#define NTHR       512

__device__ __forceinline__ float wa4(float a, float b, float c, float d, float ig) {
    float ea = __expf(a * ig), eb = __expf(b * ig);
    float ec = __expf(c * ig), ed = __expf(d * ig);
    float na = __expf(-a * ig), nb = __expf(-b * ig);
    float nc = __expf(-c * ig), nd = __expf(-d * ig);
    float s_ep  = ea + eb + ec + ed;
    float s_xep = a * ea + b * eb + c * ec + d * ed;
    float s_en  = na + nb + nc + nd;
    float s_xen = a * na + b * nb + c * nc + d * nd;
    return s_xep / s_ep - s_xen / s_en;
}

__global__ void init_kernel(unsigned* __restrict__ cur1, int n_pinb,
                            unsigned* __restrict__ cur2, int n_jb,
                            float* __restrict__ out) {
    int t = threadIdx.x;
    if (t == 0) out[0] = 0.0f;
    for (int i = t; i < n_pinb; i += blockDim.x) cur1[i] = (unsigned)i << PINB_SHIFT;
    for (int i = t; i < 2 * n_jb; i += blockDim.x) {
        int j = (i < n_jb) ? i : (i - n_jb);
        cur2[i] = (unsigned)j << JB_SHIFT;
    }
}

// ---------------- P1: partition (pin, j) by 8192-pin bucket ----------------
// EXACT R4 structure (HW-proven <=82us): separate scan and all-thread
// gbase atomic pass.
__global__ __launch_bounds__(NTHR) void p1_partition(
    const int4* __restrict__ fnp4, int NP, int n_pinb,
    uint2* __restrict__ ent1, unsigned* __restrict__ cur1)
{
    __shared__ uint2    staged[P1_CHUNK];        // 64KB
    __shared__ unsigned hist[MAX_PINB];          // 4KB
    __shared__ unsigned scn[MAX_PINB];           // 4KB
    __shared__ unsigned gbase[MAX_PINB];         // 4KB
    const int base  = blockIdx.x * P1_CHUNK;
    const int valid = min(P1_CHUNK, NP - base);  // multiple of 4 (NP%4==0)
    const int t = threadIdx.x;

    for (int b = t; b < MAX_PINB; b += NTHR) hist[b] = 0;
    __syncthreads();

    // 16 pins/thread via int4; rank pass builds histogram
    unsigned pin[16], rnk[16];
    #pragma unroll
    for (int m4 = 0; m4 < 4; ++m4) {
        int k4 = t + NTHR * m4;
        int kk = 4 * k4;
        int4 v = make_int4(0, 0, 0, 0);
        if (kk < valid) v = fnp4[(base >> 2) + k4];
        pin[4*m4+0] = (unsigned)v.x; pin[4*m4+1] = (unsigned)v.y;
        pin[4*m4+2] = (unsigned)v.z; pin[4*m4+3] = (unsigned)v.w;
    }
    #pragma unroll
    for (int m4 = 0; m4 < 4; ++m4)
        #pragma unroll
        for (int c = 0; c < 4; ++c) {
            int kk = 4 * (t + NTHR * m4) + c;
            rnk[4*m4+c] = 0;
            if (kk < valid)
                rnk[4*m4+c] = atomicAdd(&hist[pin[4*m4+c] >> PINB_SHIFT], 1u);
        }
    __syncthreads();

    // wave-0 shuffle scan over MAX_PINB buckets (16 per lane); scn only
    if (t < 64) {
        unsigned v[16], s = 0;
        #pragma unroll
        for (int i = 0; i < 16; ++i) { v[i] = hist[t * 16 + i]; s += v[i]; }
        unsigned e = s;
        #pragma unroll
        for (int off = 1; off < 64; off <<= 1) {
            unsigned u = __shfl_up(e, off, 64);
            if (t >= off) e += u;
        }
        e -= s;  // exclusive base for this lane's chunk
        #pragma unroll
        for (int i = 0; i < 16; ++i) { scn[t * 16 + i] = e; e += v[i]; }
    }
    __syncthreads();

    // all-thread cursor atomics: one per thread, latencies overlap across waves
    for (int b = t; b < n_pinb; b += NTHR)
        if (hist[b]) gbase[b] = atomicAdd(&cur1[b], hist[b]);
    __syncthreads();

    #pragma unroll
    for (int m4 = 0; m4 < 4; ++m4)
        #pragma unroll
        for (int c = 0; c < 4; ++c) {
            int kk = 4 * (t + NTHR * m4) + c;
            if (kk < valid) {
                unsigned p = pin[4*m4+c];
                staged[scn[p >> PINB_SHIFT] + rnk[4*m4+c]] =
                    make_uint2(p, (unsigned)(base + kk));
            }
        }
    __syncthreads();

    for (int k = t; k < valid; k += NTHR) {      // coalesced bucket-run writes
        uint2 e = staged[k];
        unsigned b = e.x >> PINB_SHIFT;
        ent1[gbase[b] + ((unsigned)k - scn[b])] = e;
    }
}

// ------- P2: LDS-window gather + repartition by 16384-slot j-bucket -------
// Single round over the whole 8192-entry bucket (R6 structure: 16-deep load
// pipeline, win/staged aliasing) with R4-style scan + all-thread atomics.
__global__ __launch_bounds__(NTHR) void p2_gather(
    const uint2* __restrict__ ent1, const float2* __restrict__ pos2,
    const int* __restrict__ slrx_p, const int* __restrict__ slry_p,
    int d, int NP, int n_jb,
    uint2* __restrict__ ent2, unsigned* __restrict__ cur2)
{
    const int slr = (d == 0) ? slrx_p[0] : slry_p[0];
    if (slr <= 1) return;                        // dim off: whole pipeline idle

    // union: bytes [0,32K) = win (dead after gather), [0,64K) = staged
    __shared__ __align__(16) char smem[PINB_SIZE * sizeof(uint2) + 3 * MAX_JB * 4];
    float*    win    = (float*)smem;                                  // 32KB
    uint2*    staged = (uint2*)smem;                                  // 64KB
    unsigned* hist   = (unsigned*)(smem + PINB_SIZE * sizeof(uint2)); // 2KB
    unsigned* scn    = hist + MAX_JB;                                 // 2KB
    unsigned* gbase  = scn + MAX_JB;                                  // 2KB

    const int pbase = blockIdx.x << PINB_SHIFT;
    const int valid = min(PINB_SIZE, NP - pbase);
    const int t = threadIdx.x;

    // 1) issue all entry loads up front (16/thread, latency exposed once)
    uint2 e[16];
    #pragma unroll
    for (int m = 0; m < 16; ++m) {
        int k = t + NTHR * m;
        e[m] = make_uint2(0u, 0u);
        if (k < valid) e[m] = ent1[pbase + k];
    }
    // 2) coalesced window load (overlaps entry loads) + hist zero
    for (int i = t; i < valid; i += NTHR) {
        float2 p = pos2[pbase + i];
        win[i] = d ? p.y : p.x;
    }
    if (t < MAX_JB) hist[t] = 0;                 // NTHR == MAX_JB
    __syncthreads();

    // 3) LDS gather + rank/histogram
    float yv[16]; unsigned rnk[16];
    #pragma unroll
    for (int m = 0; m < 16; ++m) {
        int k = t + NTHR * m;
        yv[m] = (k < valid) ? win[e[m].x & (PINB_SIZE - 1)] : 0.0f;
    }
    #pragma unroll
    for (int m = 0; m < 16; ++m) {
        int k = t + NTHR * m;
        rnk[m] = 0;
        if (k < valid) rnk[m] = atomicAdd(&hist[e[m].y >> JB_SHIFT], 1u);
    }
    __syncthreads();                             // all win reads + hist atomics done

    // 4) wave-0 scan (8 buckets/lane); scn only, hist preserved
    if (t < 64) {
        unsigned v[8], s = 0;
        #pragma unroll
        for (int i = 0; i < 8; ++i) { v[i] = hist[t * 8 + i]; s += v[i]; }
        unsigned ex = s;
        #pragma unroll
        for (int off = 1; off < 64; off <<= 1) {
            unsigned u = __shfl_up(ex, off, 64);
            if (t >= off) ex += u;
        }
        ex -= s;
        #pragma unroll
        for (int i = 0; i < 8; ++i) { scn[t * 8 + i] = ex; ex += v[i]; }
    }
    __syncthreads();

    // 5) all-thread cursor atomics (one per thread, overlapped)
    for (int q = t; q < n_jb; q += NTHR)
        if (hist[q]) gbase[q] = atomicAdd(&cur2[q], hist[q]);
    __syncthreads();

    // 6) stage into the union (overwrites win -- all reads completed above)
    #pragma unroll
    for (int m = 0; m < 16; ++m) {
        int k = t + NTHR * m;
        if (k < valid)
            staged[scn[e[m].y >> JB_SHIFT] + rnk[m]] =
                make_uint2(e[m].y, __float_as_uint(yv[m]));
    }
    __syncthreads();

    // 7) coalesced bucket-run writes (~17-entry = 134B runs)
    for (int k = t; k < valid; k += NTHR) {
        uint2 s2 = staged[k];
        unsigned jb = s2.x >> JB_SHIFT;
        ent2[gbase[jb] + ((unsigned)k - scn[jb])] = s2;
    }
}

// ------------- P3: LDS slot tile, per-net wa4, global reduce -------------
__global__ __launch_bounds__(NTHR) void p3_compute(
    const uint2* __restrict__ ent2, const float* __restrict__ wts,
    const float* __restrict__ ig_p,
    const int* __restrict__ slrx_p, const int* __restrict__ slry_p,
    int d, int NP, float* __restrict__ out)
{
    const int slr = (d == 0) ? slrx_p[0] : slry_p[0];
    if (slr <= 1) return;

    __shared__ float ytmp[JB_SIZE];              // 64KB
    const int jb     = blockIdx.x;
    const int base_j = jb << JB_SHIFT;
    const int nslots = min(JB_SIZE, NP - base_j);  // multiple of 4
    const int t = threadIdx.x;
    const float ig = ig_p[0];

    for (int k = t; k < nslots; k += NTHR) {     // coalesced read, LDS scatter
        uint2 e = ent2[base_j + k];
        ytmp[e.x & (JB_SIZE - 1)] = __uint_as_float(e.y);
    }
    __syncthreads();

    float val = 0.0f;
    const int nnets = nslots >> 2, bnet = base_j >> 2;
    const float4* y4 = (const float4*)ytmp;
    for (int i = t; i < nnets; i += NTHR) {
        float4 p = y4[i];                        // ds_read_b128
        val += wts[bnet + i] * wa4(p.x, p.y, p.z, p.w, ig);
    }

    #pragma unroll
    for (int off = 32; off > 0; off >>= 1) val += __shfl_down(val, off, 64);
    __syncthreads();
    if ((t & 63) == 0) ytmp[t >> 6] = val;
    __syncthreads();
    if (t == 0) {
        float s = 0.0f;
        #pragma unroll
        for (int w = 0; w < NTHR / 64; ++w) s += ytmp[w];
        atomicAdd(out, s);
    }
}

// ---------------- fallback: proven R1 gather kernel ----------------
__global__ __launch_bounds__(256) void wasll_fallback(
    const float2* __restrict__ pos, const int4* __restrict__ fnp4,
    const float* __restrict__ net_weights, const float* __restrict__ inv_gamma_p,
    const int* __restrict__ slrx_p, const int* __restrict__ slry_p,
    float* __restrict__ out, int num_nets)
{
    const float ig = inv_gamma_p[0];
    const float dx = (slrx_p[0] > 1) ? 1.0f : 0.0f;
    const float dy = (slry_p[0] > 1) ? 1.0f : 0.0f;
    int net = blockIdx.x * blockDim.x + threadIdx.x;
    float val = 0.0f;
    if (net < num_nets) {
        int4 idx = fnp4[net];
        float2 p0 = pos[idx.x], p1 = pos[idx.y], p2 = pos[idx.z], p3 = pos[idx.w];
        val = net_weights[net] * (dx * wa4(p0.x, p1.x, p2.x, p3.x, ig)
                                + dy * wa4(p0.y, p1.y, p2.y, p3.y, ig));
    }
    #pragma unroll
    for (int off = 32; off > 0; off >>= 1) val += __shfl_down(val, off, 64);
    __shared__ float smem[4];
    if ((threadIdx.x & 63) == 0) smem[threadIdx.x >> 6] = val;
    __syncthreads();
    if (threadIdx.x == 0)
        atomicAdd(out, smem[0] + smem[1] + smem[2] + smem[3]);
}

__global__ void zero_out_kernel(float* __restrict__ out) { out[0] = 0.0f; }

extern "C" void kernel_launch(void* const* d_in, const int* in_sizes, int n_in,
                              void* d_out, int out_size, void* d_ws, size_t ws_size,
                              hipStream_t stream) {
    const float* posf        = (const float*)d_in[0];
    const int*   fnp         = (const int*)d_in[1];
    const float* net_weights = (const float*)d_in[4];
    const float* inv_gamma   = (const float*)d_in[7];
    const int*   slrx        = (const int*)d_in[8];
    const int*   slry        = (const int*)d_in[9];
    float*       out         = (float*)d_out;
    const int    N  = in_sizes[4];
    const int    NP = in_sizes[1];

    const int n_pinb = (NP + PINB_SIZE - 1) >> PINB_SHIFT;
    const int n_jb   = (NP + JB_SIZE - 1) >> JB_SHIFT;

    size_t off = 0;
    auto carve = [&](size_t bytes) { size_t o = off; off += (bytes + 255) & ~size_t(255); return o; };
    size_t o_ent1 = carve((size_t)n_pinb * PINB_SIZE * sizeof(uint2));
    size_t o_ent2 = carve((size_t)n_jb * JB_SIZE * sizeof(uint2));
    size_t o_cur1 = carve((size_t)n_pinb * sizeof(unsigned));
    size_t o_cur2 = carve((size_t)2 * n_jb * sizeof(unsigned));  // double-buffered per dim

    const bool ok = (NP == 4 * N) && (NP % 4 == 0) &&
                    (n_pinb <= MAX_PINB) && (n_jb <= MAX_JB) && (off <= ws_size);
    if (!ok) {
        hipLaunchKernelGGL(zero_out_kernel, dim3(1), dim3(1), 0, stream, out);
        const int block = 256, grid = (N + block - 1) / block;
        hipLaunchKernelGGL(wasll_fallback, dim3(grid), dim3(block), 0, stream,
                           (const float2*)posf, (const int4*)fnp, net_weights,
                           inv_gamma, slrx, slry, out, N);
        return;
    }

    char* ws = (char*)d_ws;
    uint2*    ent1 = (uint2*)(ws + o_ent1);
    uint2*    ent2 = (uint2*)(ws + o_ent2);
    unsigned* cur1 = (unsigned*)(ws + o_cur1);
    unsigned* cur2 = (unsigned*)(ws + o_cur2);

    hipLaunchKernelGGL(init_kernel, dim3(1), dim3(1024), 0, stream,
                       cur1, n_pinb, cur2, n_jb, out);

    const int g1 = (NP + P1_CHUNK - 1) / P1_CHUNK;
    hipLaunchKernelGGL(p1_partition, dim3(g1), dim3(NTHR), 0, stream,
                       (const int4*)fnp, NP, n_pinb, ent1, cur1);

    // d = 0 (x): early-exits when num_slrX <= 1
    hipLaunchKernelGGL(p2_gather, dim3(n_pinb), dim3(NTHR), 0, stream,
                       ent1, (const float2*)posf, slrx, slry, 0, NP, n_jb, ent2, cur2);
    hipLaunchKernelGGL(p3_compute, dim3(n_jb), dim3(NTHR), 0, stream,
                       ent2, net_weights, inv_gamma, slrx, slry, 0, NP, out);

    // d = 1 (y): second cur2 buffer, no reinit launch needed
    hipLaunchKernelGGL(p2_gather, dim3(n_pinb), dim3(NTHR), 0, stream,
                       ent1, (const float2*)posf, slrx, slry, 1, NP, n_jb, ent2, cur2 + n_jb);
    hipLaunchKernelGGL(p3_compute, dim3(n_jb), dim3(NTHR), 0, stream,
                       ent2, net_weights, inv_gamma, slrx, slry, 1, NP, out);
}

// Round 5
// 274.020 us; speedup vs baseline: 2.6425x; 1.0059x over previous
//
#include <hip/hip_runtime.h>
#include <stdint.h>

// WASLL R9: residency reshape -- 1024-thread blocks, 8-deep arrays.
// R8 confirmed the R5-R7 poison was the fused wave-0 conditional cursor
// atomics (serialized device-scope round-trips on the critical path), NOT
// 1024-thread blocks per se; the other R5 poison was the (1024,8) VGPR cap.
// With both removed, the occupancy lever is safe: p2 sits at Occ 33%
// (2 blocks/CU x 8 waves = 50% cap from 70KB LDS), HBM 26%, VALU 10% --
// latency-bound. 1024 threads x 8 items/thread keeps the exact same LDS
// footprint, phase structure, and the allocator-proven 8-deep register
// shape (R4 p2: VGPR 52, no spill), but doubles residency to 32 waves/CU.
// __launch_bounds__(1024) implies <=128 VGPR -- ample for 8-deep.

#define PINB_SHIFT 13
#define PINB_SIZE  (1 << PINB_SHIFT)      // 8192 pins/bucket = 32KB window
#define MAX_PINB   1024
#define JB_SHIFT   14
#define JB_SIZE    (1 << JB_SHIFT)        // 16384 slots/j-bucket (4096 nets)
#define MAX_JB     512
#define P1_CHUNK   8192                   // entries per P1 block
#define NTHR       1024

__device__ __forceinline__ float wa4(float a, float b, float c, float d, float ig) {
    float ea = __expf(a * ig), eb = __expf(b * ig);
    float ec = __expf(c * ig), ed = __expf(d * ig);
    float na = __expf(-a * ig), nb = __expf(-b * ig);
    float nc = __expf(-c * ig), nd = __expf(-d * ig);
    float s_ep  = ea + eb + ec + ed;
    float s_xep = a * ea + b * eb + c * ec + d * ed;
    float s_en  = na + nb + nc + nd;
    float s_xen = a * na + b * nb + c * nc + d * nd;
    return s_xep / s_ep - s_xen / s_en;
}

__global__ void init_kernel(unsigned* __restrict__ cur1, int n_pinb,
                            unsigned* __restrict__ cur2, int n_jb,
                            float* __restrict__ out) {
    int t = threadIdx.x;
    if (t == 0) out[0] = 0.0f;
    for (int i = t; i < n_pinb; i += blockDim.x) cur1[i] = (unsigned)i << PINB_SHIFT;
    for (int i = t; i < 2 * n_jb; i += blockDim.x) {
        int j = (i < n_jb) ? i : (i - n_jb);
        cur2[i] = (unsigned)j << JB_SHIFT;
    }
}

// ---------------- P1: partition (pin, j) by 8192-pin bucket ----------------
// R4 phase structure (scan separate, all-thread gbase atomics), 1024 threads.
__global__ __launch_bounds__(NTHR) void p1_partition(
    const int4* __restrict__ fnp4, int NP, int n_pinb,
    uint2* __restrict__ ent1, unsigned* __restrict__ cur1)
{
    __shared__ uint2    staged[P1_CHUNK];        // 64KB
    __shared__ unsigned hist[MAX_PINB];          // 4KB
    __shared__ unsigned scn[MAX_PINB];           // 4KB
    __shared__ unsigned gbase[MAX_PINB];         // 4KB
    const int base  = blockIdx.x * P1_CHUNK;
    const int valid = min(P1_CHUNK, NP - base);  // multiple of 4 (NP%4==0)
    const int t = threadIdx.x;

    for (int b = t; b < MAX_PINB; b += NTHR) hist[b] = 0;
    __syncthreads();

    // 8 pins/thread via int4; rank pass builds histogram
    unsigned pin[8], rnk[8];
    #pragma unroll
    for (int m4 = 0; m4 < 2; ++m4) {
        int k4 = t + NTHR * m4;
        int kk = 4 * k4;
        int4 v = make_int4(0, 0, 0, 0);
        if (kk < valid) v = fnp4[(base >> 2) + k4];
        pin[4*m4+0] = (unsigned)v.x; pin[4*m4+1] = (unsigned)v.y;
        pin[4*m4+2] = (unsigned)v.z; pin[4*m4+3] = (unsigned)v.w;
    }
    #pragma unroll
    for (int m4 = 0; m4 < 2; ++m4)
        #pragma unroll
        for (int c = 0; c < 4; ++c) {
            int kk = 4 * (t + NTHR * m4) + c;
            rnk[4*m4+c] = 0;
            if (kk < valid)
                rnk[4*m4+c] = atomicAdd(&hist[pin[4*m4+c] >> PINB_SHIFT], 1u);
        }
    __syncthreads();

    // wave-0 shuffle scan over MAX_PINB buckets (16 per lane); scn only
    if (t < 64) {
        unsigned v[16], s = 0;
        #pragma unroll
        for (int i = 0; i < 16; ++i) { v[i] = hist[t * 16 + i]; s += v[i]; }
        unsigned e = s;
        #pragma unroll
        for (int off = 1; off < 64; off <<= 1) {
            unsigned u = __shfl_up(e, off, 64);
            if (t >= off) e += u;
        }
        e -= s;  // exclusive base for this lane's chunk
        #pragma unroll
        for (int i = 0; i < 16; ++i) { scn[t * 16 + i] = e; e += v[i]; }
    }
    __syncthreads();

    // all-thread cursor atomics: one per thread, latencies overlap across waves
    for (int b = t; b < n_pinb; b += NTHR)
        if (hist[b]) gbase[b] = atomicAdd(&cur1[b], hist[b]);
    __syncthreads();

    #pragma unroll
    for (int m4 = 0; m4 < 2; ++m4)
        #pragma unroll
        for (int c = 0; c < 4; ++c) {
            int kk = 4 * (t + NTHR * m4) + c;
            if (kk < valid) {
                unsigned p = pin[4*m4+c];
                staged[scn[p >> PINB_SHIFT] + rnk[4*m4+c]] =
                    make_uint2(p, (unsigned)(base + kk));
            }
        }
    __syncthreads();

    for (int k = t; k < valid; k += NTHR) {      // coalesced bucket-run writes
        uint2 e = staged[k];
        unsigned b = e.x >> PINB_SHIFT;
        ent1[gbase[b] + ((unsigned)k - scn[b])] = e;
    }
}

// ------- P2: LDS-window gather + repartition by 16384-slot j-bucket -------
// Single round over the whole 8192-entry bucket; win and staged alias.
__global__ __launch_bounds__(NTHR) void p2_gather(
    const uint2* __restrict__ ent1, const float2* __restrict__ pos2,
    const int* __restrict__ slrx_p, const int* __restrict__ slry_p,
    int d, int NP, int n_jb,
    uint2* __restrict__ ent2, unsigned* __restrict__ cur2)
{
    const int slr = (d == 0) ? slrx_p[0] : slry_p[0];
    if (slr <= 1) return;                        // dim off: whole pipeline idle

    // union: bytes [0,32K) = win (dead after gather), [0,64K) = staged
    __shared__ __align__(16) char smem[PINB_SIZE * sizeof(uint2) + 3 * MAX_JB * 4];
    float*    win    = (float*)smem;                                  // 32KB
    uint2*    staged = (uint2*)smem;                                  // 64KB
    unsigned* hist   = (unsigned*)(smem + PINB_SIZE * sizeof(uint2)); // 2KB
    unsigned* scn    = hist + MAX_JB;                                 // 2KB
    unsigned* gbase  = scn + MAX_JB;                                  // 2KB

    const int pbase = blockIdx.x << PINB_SHIFT;
    const int valid = min(PINB_SIZE, NP - pbase);
    const int t = threadIdx.x;

    // 1) issue all entry loads up front (8/thread, latency exposed once)
    uint2 e[8];
    #pragma unroll
    for (int m = 0; m < 8; ++m) {
        int k = t + NTHR * m;
        e[m] = make_uint2(0u, 0u);
        if (k < valid) e[m] = ent1[pbase + k];
    }
    // 2) coalesced window load (overlaps entry loads) + hist zero
    for (int i = t; i < valid; i += NTHR) {
        float2 p = pos2[pbase + i];
        win[i] = d ? p.y : p.x;
    }
    if (t < MAX_JB) hist[t] = 0;
    __syncthreads();

    // 3) LDS gather + rank/histogram
    float yv[8]; unsigned rnk[8];
    #pragma unroll
    for (int m = 0; m < 8; ++m) {
        int k = t + NTHR * m;
        yv[m] = (k < valid) ? win[e[m].x & (PINB_SIZE - 1)] : 0.0f;
    }
    #pragma unroll
    for (int m = 0; m < 8; ++m) {
        int k = t + NTHR * m;
        rnk[m] = 0;
        if (k < valid) rnk[m] = atomicAdd(&hist[e[m].y >> JB_SHIFT], 1u);
    }
    __syncthreads();                             // all win reads + hist atomics done

    // 4) wave-0 scan (8 buckets/lane); scn only, hist preserved
    if (t < 64) {
        unsigned v[8], s = 0;
        #pragma unroll
        for (int i = 0; i < 8; ++i) { v[i] = hist[t * 8 + i]; s += v[i]; }
        unsigned ex = s;
        #pragma unroll
        for (int off = 1; off < 64; off <<= 1) {
            unsigned u = __shfl_up(ex, off, 64);
            if (t >= off) ex += u;
        }
        ex -= s;
        #pragma unroll
        for (int i = 0; i < 8; ++i) { scn[t * 8 + i] = ex; ex += v[i]; }
    }
    __syncthreads();

    // 5) all-thread cursor atomics (one per thread, overlapped)
    for (int q = t; q < n_jb; q += NTHR)
        if (hist[q]) gbase[q] = atomicAdd(&cur2[q], hist[q]);
    __syncthreads();

    // 6) stage into the union (overwrites win -- all reads completed above)
    #pragma unroll
    for (int m = 0; m < 8; ++m) {
        int k = t + NTHR * m;
        if (k < valid)
            staged[scn[e[m].y >> JB_SHIFT] + rnk[m]] =
                make_uint2(e[m].y, __float_as_uint(yv[m]));
    }
    __syncthreads();

    // 7) coalesced bucket-run writes (~17-entry = 134B runs)
    for (int k = t; k < valid; k += NTHR) {
        uint2 s2 = staged[k];
        unsigned jb = s2.x >> JB_SHIFT;
        ent2[gbase[jb] + ((unsigned)k - scn[jb])] = s2;
    }
}

// ------------- P3: LDS slot tile, per-net wa4, global reduce -------------
__global__ __launch_bounds__(NTHR) void p3_compute(
    const uint2* __restrict__ ent2, const float* __restrict__ wts,
    const float* __restrict__ ig_p,
    const int* __restrict__ slrx_p, const int* __restrict__ slry_p,
    int d, int NP, float* __restrict__ out)
{
    const int slr = (d == 0) ? slrx_p[0] : slry_p[0];
    if (slr <= 1) return;

    __shared__ float ytmp[JB_SIZE];              // 64KB
    const int jb     = blockIdx.x;
    const int base_j = jb << JB_SHIFT;
    const int nslots = min(JB_SIZE, NP - base_j);  // multiple of 4
    const int t = threadIdx.x;
    const float ig = ig_p[0];

    for (int k = t; k < nslots; k += NTHR) {     // coalesced read, LDS scatter
        uint2 e = ent2[base_j + k];
        ytmp[e.x & (JB_SIZE - 1)] = __uint_as_float(e.y);
    }
    __syncthreads();

    float val = 0.0f;
    const int nnets = nslots >> 2, bnet = base_j >> 2;
    const float4* y4 = (const float4*)ytmp;
    for (int i = t; i < nnets; i += NTHR) {
        float4 p = y4[i];                        // ds_read_b128
        val += wts[bnet + i] * wa4(p.x, p.y, p.z, p.w, ig);
    }

    #pragma unroll
    for (int off = 32; off > 0; off >>= 1) val += __shfl_down(val, off, 64);
    __syncthreads();
    if ((t & 63) == 0) ytmp[t >> 6] = val;
    __syncthreads();
    if (t == 0) {
        float s = 0.0f;
        #pragma unroll
        for (int w = 0; w < NTHR / 64; ++w) s += ytmp[w];
        atomicAdd(out, s);
    }
}

// ---------------- fallback: proven R1 gather kernel ----------------
__global__ __launch_bounds__(256) void wasll_fallback(
    const float2* __restrict__ pos, const int4* __restrict__ fnp4,
    const float* __restrict__ net_weights, const float* __restrict__ inv_gamma_p,
    const int* __restrict__ slrx_p, const int* __restrict__ slry_p,
    float* __restrict__ out, int num_nets)
{
    const float ig = inv_gamma_p[0];
    const float dx = (slrx_p[0] > 1) ? 1.0f : 0.0f;
    const float dy = (slry_p[0] > 1) ? 1.0f : 0.0f;
    int net = blockIdx.x * blockDim.x + threadIdx.x;
    float val = 0.0f;
    if (net < num_nets) {
        int4 idx = fnp4[net];
        float2 p0 = pos[idx.x], p1 = pos[idx.y], p2 = pos[idx.z], p3 = pos[idx.w];
        val = net_weights[net] * (dx * wa4(p0.x, p1.x, p2.x, p3.x, ig)
                                + dy * wa4(p0.y, p1.y, p2.y, p3.y, ig));
    }
    #pragma unroll
    for (int off = 32; off > 0; off >>= 1) val += __shfl_down(val, off, 64);
    __shared__ float smem[4];
    if ((threadIdx.x & 63) == 0) smem[threadIdx.x >> 6] = val;
    __syncthreads();
    if (threadIdx.x == 0)
        atomicAdd(out, smem[0] + smem[1] + smem[2] + smem[3]);
}

__global__ void zero_out_kernel(float* __restrict__ out) { out[0] = 0.0f; }

extern "C" void kernel_launch(void* const* d_in, const int* in_sizes, int n_in,
                              void* d_out, int out_size, void* d_ws, size_t ws_size,
                              hipStream_t stream) {
    const float* posf        = (const float*)d_in[0];
    const int*   fnp         = (const int*)d_in[1];
    const float* net_weights = (const float*)d_in[4];
    const float* inv_gamma   = (const float*)d_in[7];
    const int*   slrx        = (const int*)d_in[8];
    const int*   slry        = (const int*)d_in[9];
    float*       out         = (float*)d_out;
    const int    N  = in_sizes[4];
    const int    NP = in_sizes[1];

    const int n_pinb = (NP + PINB_SIZE - 1) >> PINB_SHIFT;
    const int n_jb   = (NP + JB_SIZE - 1) >> JB_SHIFT;

    size_t off = 0;
    auto carve = [&](size_t bytes) { size_t o = off; off += (bytes + 255) & ~size_t(255); return o; };
    size_t o_ent1 = carve((size_t)n_pinb * PINB_SIZE * sizeof(uint2));
    size_t o_ent2 = carve((size_t)n_jb * JB_SIZE * sizeof(uint2));
    size_t o_cur1 = carve((size_t)n_pinb * sizeof(unsigned));
    size_t o_cur2 = carve((size_t)2 * n_jb * sizeof(unsigned));  // double-buffered per dim

    const bool ok = (NP == 4 * N) && (NP % 4 == 0) &&
                    (n_pinb <= MAX_PINB) && (n_jb <= MAX_JB) && (off <= ws_size);
    if (!ok) {
        hipLaunchKernelGGL(zero_out_kernel, dim3(1), dim3(1), 0, stream, out);
        const int block = 256, grid = (N + block - 1) / block;
        hipLaunchKernelGGL(wasll_fallback, dim3(grid), dim3(block), 0, stream,
                           (const float2*)posf, (const int4*)fnp, net_weights,
                           inv_gamma, slrx, slry, out, N);
        return;
    }

    char* ws = (char*)d_ws;
    uint2*    ent1 = (uint2*)(ws + o_ent1);
    uint2*    ent2 = (uint2*)(ws + o_ent2);
    unsigned* cur1 = (unsigned*)(ws + o_cur1);
    unsigned* cur2 = (unsigned*)(ws + o_cur2);

    hipLaunchKernelGGL(init_kernel, dim3(1), dim3(1024), 0, stream,
                       cur1, n_pinb, cur2, n_jb, out);

    const int g1 = (NP + P1_CHUNK - 1) / P1_CHUNK;
    hipLaunchKernelGGL(p1_partition, dim3(g1), dim3(NTHR), 0, stream,
                       (const int4*)fnp, NP, n_pinb, ent1, cur1);

    // d = 0 (x): early-exits when num_slrX <= 1
    hipLaunchKernelGGL(p2_gather, dim3(n_pinb), dim3(NTHR), 0, stream,
                       ent1, (const float2*)posf, slrx, slry, 0, NP, n_jb, ent2, cur2);
    hipLaunchKernelGGL(p3_compute, dim3(n_jb), dim3(NTHR), 0, stream,
                       ent2, net_weights, inv_gamma, slrx, slry, 0, NP, out);

    // d = 1 (y): second cur2 buffer, no reinit launch needed
    hipLaunchKernelGGL(p2_gather, dim3(n_pinb), dim3(NTHR), 0, stream,
                       ent1, (const float2*)posf, slrx, slry, 1, NP, n_jb, ent2, cur2 + n_jb);
    hipLaunchKernelGGL(p3_compute, dim3(n_jb), dim3(NTHR), 0, stream,
                       ent2, net_weights, inv_gamma, slrx, slry, 1, NP, out);
}

// Round 6
// 273.110 us; speedup vs baseline: 2.6514x; 1.0033x over previous
//
#include <hip/hip_runtime.h>
#include <stdint.h>

// WASLL R10: split p2 buckets across two blocks -- 4 barrier domains/CU.
// R9 post-mortem: doubling waves-per-block raised Occ 33->66% but p2 got
// SLOWER (65->70us): (a) VGPR_Count=28 with 32+ live regs and flat
// FETCH/WRITE = compiler rematerialized e[] via extra L2 loads; (b) waves
// in the SAME block share one barrier domain -- a syncthreads drains all of
// them together, so added waves don't cover phase latency; only independent
// blocks do. R10 tests the untested axis: p2 = 512 thr x 8-deep (allocator-
// proven shape, no remat) over HALF a bucket (4096 entries), win 32KB fully
// aliased with staged 32KB + 6KB bookkeeping = 38KB -> 4 blocks/CU, 1954
// blocks. Each drain now covered by 3 independent blocks. Cost: window pos
// read doubles (L3-hit), output runs halve to ~8.4 entries (R4-proven OK).
// p1/p3 keep R9's 1024-thread shape (R9 total beat R8 via p1/p3).

#define PINB_SHIFT 13
#define PINB_SIZE  (1 << PINB_SHIFT)      // 8192 pins/bucket = 32KB window
#define MAX_PINB   1024
#define JB_SHIFT   14
#define JB_SIZE    (1 << JB_SHIFT)        // 16384 slots/j-bucket (4096 nets)
#define MAX_JB     512
#define P1_CHUNK   8192                   // entries per P1 block
#define P2_CHUNK   4096                   // entries per P2 block (half bucket)
#define NTHR       1024                   // p1/p3 block size
#define NTHR2      512                    // p2 block size

__device__ __forceinline__ float wa4(float a, float b, float c, float d, float ig) {
    float ea = __expf(a * ig), eb = __expf(b * ig);
    float ec = __expf(c * ig), ed = __expf(d * ig);
    float na = __expf(-a * ig), nb = __expf(-b * ig);
    float nc = __expf(-c * ig), nd = __expf(-d * ig);
    float s_ep  = ea + eb + ec + ed;
    float s_xep = a * ea + b * eb + c * ec + d * ed;
    float s_en  = na + nb + nc + nd;
    float s_xen = a * na + b * nb + c * nc + d * nd;
    return s_xep / s_ep - s_xen / s_en;
}

__global__ void init_kernel(unsigned* __restrict__ cur1, int n_pinb,
                            unsigned* __restrict__ cur2, int n_jb,
                            float* __restrict__ out) {
    int t = threadIdx.x;
    if (t == 0) out[0] = 0.0f;
    for (int i = t; i < n_pinb; i += blockDim.x) cur1[i] = (unsigned)i << PINB_SHIFT;
    for (int i = t; i < 2 * n_jb; i += blockDim.x) {
        int j = (i < n_jb) ? i : (i - n_jb);
        cur2[i] = (unsigned)j << JB_SHIFT;
    }
}

// ---------------- P1: partition (pin, j) by 8192-pin bucket ----------------
// R9 shape: 1024 threads, 8 pins/thread, scan separate, all-thread atomics.
__global__ __launch_bounds__(NTHR) void p1_partition(
    const int4* __restrict__ fnp4, int NP, int n_pinb,
    uint2* __restrict__ ent1, unsigned* __restrict__ cur1)
{
    __shared__ uint2    staged[P1_CHUNK];        // 64KB
    __shared__ unsigned hist[MAX_PINB];          // 4KB
    __shared__ unsigned scn[MAX_PINB];           // 4KB
    __shared__ unsigned gbase[MAX_PINB];         // 4KB
    const int base  = blockIdx.x * P1_CHUNK;
    const int valid = min(P1_CHUNK, NP - base);  // multiple of 4 (NP%4==0)
    const int t = threadIdx.x;

    for (int b = t; b < MAX_PINB; b += NTHR) hist[b] = 0;
    __syncthreads();

    // 8 pins/thread via int4; rank pass builds histogram
    unsigned pin[8], rnk[8];
    #pragma unroll
    for (int m4 = 0; m4 < 2; ++m4) {
        int k4 = t + NTHR * m4;
        int kk = 4 * k4;
        int4 v = make_int4(0, 0, 0, 0);
        if (kk < valid) v = fnp4[(base >> 2) + k4];
        pin[4*m4+0] = (unsigned)v.x; pin[4*m4+1] = (unsigned)v.y;
        pin[4*m4+2] = (unsigned)v.z; pin[4*m4+3] = (unsigned)v.w;
    }
    #pragma unroll
    for (int m4 = 0; m4 < 2; ++m4)
        #pragma unroll
        for (int c = 0; c < 4; ++c) {
            int kk = 4 * (t + NTHR * m4) + c;
            rnk[4*m4+c] = 0;
            if (kk < valid)
                rnk[4*m4+c] = atomicAdd(&hist[pin[4*m4+c] >> PINB_SHIFT], 1u);
        }
    __syncthreads();

    // wave-0 shuffle scan over MAX_PINB buckets (16 per lane); scn only
    if (t < 64) {
        unsigned v[16], s = 0;
        #pragma unroll
        for (int i = 0; i < 16; ++i) { v[i] = hist[t * 16 + i]; s += v[i]; }
        unsigned e = s;
        #pragma unroll
        for (int off = 1; off < 64; off <<= 1) {
            unsigned u = __shfl_up(e, off, 64);
            if (t >= off) e += u;
        }
        e -= s;  // exclusive base for this lane's chunk
        #pragma unroll
        for (int i = 0; i < 16; ++i) { scn[t * 16 + i] = e; e += v[i]; }
    }
    __syncthreads();

    // all-thread cursor atomics: one per thread, latencies overlap across waves
    for (int b = t; b < n_pinb; b += NTHR)
        if (hist[b]) gbase[b] = atomicAdd(&cur1[b], hist[b]);
    __syncthreads();

    #pragma unroll
    for (int m4 = 0; m4 < 2; ++m4)
        #pragma unroll
        for (int c = 0; c < 4; ++c) {
            int kk = 4 * (t + NTHR * m4) + c;
            if (kk < valid) {
                unsigned p = pin[4*m4+c];
                staged[scn[p >> PINB_SHIFT] + rnk[4*m4+c]] =
                    make_uint2(p, (unsigned)(base + kk));
            }
        }
    __syncthreads();

    for (int k = t; k < valid; k += NTHR) {      // coalesced bucket-run writes
        uint2 e = staged[k];
        unsigned b = e.x >> PINB_SHIFT;
        ent1[gbase[b] + ((unsigned)k - scn[b])] = e;
    }
}

// ------- P2: LDS-window gather + repartition by 16384-slot j-bucket -------
// Half-bucket per block: 512 thr x 8 entries, full 8192-pin window.
// win (32KB) fully aliases staged (32KB): gather reads complete before the
// post-scan barrier; staging writes after it.
__global__ __launch_bounds__(NTHR2) void p2_gather(
    const uint2* __restrict__ ent1, const float2* __restrict__ pos2,
    const int* __restrict__ slrx_p, const int* __restrict__ slry_p,
    int d, int NP, int n_jb,
    uint2* __restrict__ ent2, unsigned* __restrict__ cur2)
{
    const int slr = (d == 0) ? slrx_p[0] : slry_p[0];
    if (slr <= 1) return;                        // dim off: whole pipeline idle

    // union: bytes [0,32K) = win == staged; bookkeeping above
    __shared__ __align__(16) char smem[PINB_SIZE * 4 + 3 * MAX_JB * 4];  // 38KB
    float*    win    = (float*)smem;                           // 32KB
    uint2*    staged = (uint2*)smem;                           // 32KB (4096)
    unsigned* hist   = (unsigned*)(smem + PINB_SIZE * 4);      // 2KB
    unsigned* scn    = hist + MAX_JB;                          // 2KB
    unsigned* gbase  = scn + MAX_JB;                           // 2KB

    const int q       = blockIdx.x >> 1;         // pin-bucket
    const int h       = blockIdx.x & 1;          // which half of the bucket
    const int pbase   = q << PINB_SHIFT;
    const int count_b = min(PINB_SIZE, NP - pbase);     // pins in window
    const int ebase   = pbase + h * P2_CHUNK;           // this block's entries
    const int valid   = min(P2_CHUNK, NP - ebase);      // may be <=0 (no-op)
    const int t = threadIdx.x;

    // 1) issue all entry loads up front (8/thread, latency exposed once)
    uint2 e[8];
    #pragma unroll
    for (int m = 0; m < 8; ++m) {
        int k = t + NTHR2 * m;
        e[m] = make_uint2(0u, 0u);
        if (k < valid) e[m] = ent1[ebase + k];
    }
    // 2) coalesced full-window load (overlaps entry loads) + hist zero
    for (int i = t; i < count_b; i += NTHR2) {
        float2 p = pos2[pbase + i];
        win[i] = d ? p.y : p.x;
    }
    if (t < MAX_JB) hist[t] = 0;                 // NTHR2 == MAX_JB
    __syncthreads();

    // 3) LDS gather + rank/histogram
    float yv[8]; unsigned rnk[8];
    #pragma unroll
    for (int m = 0; m < 8; ++m) {
        int k = t + NTHR2 * m;
        yv[m] = (k < valid) ? win[e[m].x & (PINB_SIZE - 1)] : 0.0f;
    }
    #pragma unroll
    for (int m = 0; m < 8; ++m) {
        int k = t + NTHR2 * m;
        rnk[m] = 0;
        if (k < valid) rnk[m] = atomicAdd(&hist[e[m].y >> JB_SHIFT], 1u);
    }
    __syncthreads();                             // all win reads + hist atomics done

    // 4) wave-0 scan (8 buckets/lane); scn only, hist preserved
    if (t < 64) {
        unsigned v[8], s = 0;
        #pragma unroll
        for (int i = 0; i < 8; ++i) { v[i] = hist[t * 8 + i]; s += v[i]; }
        unsigned ex = s;
        #pragma unroll
        for (int off = 1; off < 64; off <<= 1) {
            unsigned u = __shfl_up(ex, off, 64);
            if (t >= off) ex += u;
        }
        ex -= s;
        #pragma unroll
        for (int i = 0; i < 8; ++i) { scn[t * 8 + i] = ex; ex += v[i]; }
    }
    __syncthreads();

    // 5) all-thread cursor atomics (one per thread, overlapped)
    for (int q2 = t; q2 < n_jb; q2 += NTHR2)
        if (hist[q2]) gbase[q2] = atomicAdd(&cur2[q2], hist[q2]);
    __syncthreads();

    // 6) stage into the union (overwrites win -- all reads completed above)
    #pragma unroll
    for (int m = 0; m < 8; ++m) {
        int k = t + NTHR2 * m;
        if (k < valid)
            staged[scn[e[m].y >> JB_SHIFT] + rnk[m]] =
                make_uint2(e[m].y, __float_as_uint(yv[m]));
    }
    __syncthreads();

    // 7) coalesced bucket-run writes (~8.4-entry runs)
    for (int k = t; k < valid; k += NTHR2) {
        uint2 s2 = staged[k];
        unsigned jb = s2.x >> JB_SHIFT;
        ent2[gbase[jb] + ((unsigned)k - scn[jb])] = s2;
    }
}

// ------------- P3: LDS slot tile, per-net wa4, global reduce -------------
__global__ __launch_bounds__(NTHR) void p3_compute(
    const uint2* __restrict__ ent2, const float* __restrict__ wts,
    const float* __restrict__ ig_p,
    const int* __restrict__ slrx_p, const int* __restrict__ slry_p,
    int d, int NP, float* __restrict__ out)
{
    const int slr = (d == 0) ? slrx_p[0] : slry_p[0];
    if (slr <= 1) return;

    __shared__ float ytmp[JB_SIZE];              // 64KB
    const int jb     = blockIdx.x;
    const int base_j = jb << JB_SHIFT;
    const int nslots = min(JB_SIZE, NP - base_j);  // multiple of 4
    const int t = threadIdx.x;
    const float ig = ig_p[0];

    for (int k = t; k < nslots; k += NTHR) {     // coalesced read, LDS scatter
        uint2 e = ent2[base_j + k];
        ytmp[e.x & (JB_SIZE - 1)] = __uint_as_float(e.y);
    }
    __syncthreads();

    float val = 0.0f;
    const int nnets = nslots >> 2, bnet = base_j >> 2;
    const float4* y4 = (const float4*)ytmp;
    for (int i = t; i < nnets; i += NTHR) {
        float4 p = y4[i];                        // ds_read_b128
        val += wts[bnet + i] * wa4(p.x, p.y, p.z, p.w, ig);
    }

    #pragma unroll
    for (int off = 32; off > 0; off >>= 1) val += __shfl_down(val, off, 64);
    __syncthreads();
    if ((t & 63) == 0) ytmp[t >> 6] = val;
    __syncthreads();
    if (t == 0) {
        float s = 0.0f;
        #pragma unroll
        for (int w = 0; w < NTHR / 64; ++w) s += ytmp[w];
        atomicAdd(out, s);
    }
}

// ---------------- fallback: proven R1 gather kernel ----------------
__global__ __launch_bounds__(256) void wasll_fallback(
    const float2* __restrict__ pos, const int4* __restrict__ fnp4,
    const float* __restrict__ net_weights, const float* __restrict__ inv_gamma_p,
    const int* __restrict__ slrx_p, const int* __restrict__ slry_p,
    float* __restrict__ out, int num_nets)
{
    const float ig = inv_gamma_p[0];
    const float dx = (slrx_p[0] > 1) ? 1.0f : 0.0f;
    const float dy = (slry_p[0] > 1) ? 1.0f : 0.0f;
    int net = blockIdx.x * blockDim.x + threadIdx.x;
    float val = 0.0f;
    if (net < num_nets) {
        int4 idx = fnp4[net];
        float2 p0 = pos[idx.x], p1 = pos[idx.y], p2 = pos[idx.z], p3 = pos[idx.w];
        val = net_weights[net] * (dx * wa4(p0.x, p1.x, p2.x, p3.x, ig)
                                + dy * wa4(p0.y, p1.y, p2.y, p3.y, ig));
    }
    #pragma unroll
    for (int off = 32; off > 0; off >>= 1) val += __shfl_down(val, off, 64);
    __shared__ float smem[4];
    if ((threadIdx.x & 63) == 0) smem[threadIdx.x >> 6] = val;
    __syncthreads();
    if (threadIdx.x == 0)
        atomicAdd(out, smem[0] + smem[1] + smem[2] + smem[3]);
}

__global__ void zero_out_kernel(float* __restrict__ out) { out[0] = 0.0f; }

extern "C" void kernel_launch(void* const* d_in, const int* in_sizes, int n_in,
                              void* d_out, int out_size, void* d_ws, size_t ws_size,
                              hipStream_t stream) {
    const float* posf        = (const float*)d_in[0];
    const int*   fnp         = (const int*)d_in[1];
    const float* net_weights = (const float*)d_in[4];
    const float* inv_gamma   = (const float*)d_in[7];
    const int*   slrx        = (const int*)d_in[8];
    const int*   slry        = (const int*)d_in[9];
    float*       out         = (float*)d_out;
    const int    N  = in_sizes[4];
    const int    NP = in_sizes[1];

    const int n_pinb = (NP + PINB_SIZE - 1) >> PINB_SHIFT;
    const int n_jb   = (NP + JB_SIZE - 1) >> JB_SHIFT;

    size_t off = 0;
    auto carve = [&](size_t bytes) { size_t o = off; off += (bytes + 255) & ~size_t(255); return o; };
    size_t o_ent1 = carve((size_t)n_pinb * PINB_SIZE * sizeof(uint2));
    size_t o_ent2 = carve((size_t)n_jb * JB_SIZE * sizeof(uint2));
    size_t o_cur1 = carve((size_t)n_pinb * sizeof(unsigned));
    size_t o_cur2 = carve((size_t)2 * n_jb * sizeof(unsigned));  // double-buffered per dim

    const bool ok = (NP == 4 * N) && (NP % 4 == 0) &&
                    (n_pinb <= MAX_PINB) && (n_jb <= MAX_JB) && (off <= ws_size);
    if (!ok) {
        hipLaunchKernelGGL(zero_out_kernel, dim3(1), dim3(1), 0, stream, out);
        const int block = 256, grid = (N + block - 1) / block;
        hipLaunchKernelGGL(wasll_fallback, dim3(grid), dim3(block), 0, stream,
                           (const float2*)posf, (const int4*)fnp, net_weights,
                           inv_gamma, slrx, slry, out, N);
        return;
    }

    char* ws = (char*)d_ws;
    uint2*    ent1 = (uint2*)(ws + o_ent1);
    uint2*    ent2 = (uint2*)(ws + o_ent2);
    unsigned* cur1 = (unsigned*)(ws + o_cur1);
    unsigned* cur2 = (unsigned*)(ws + o_cur2);

    hipLaunchKernelGGL(init_kernel, dim3(1), dim3(1024), 0, stream,
                       cur1, n_pinb, cur2, n_jb, out);

    const int g1 = (NP + P1_CHUNK - 1) / P1_CHUNK;
    hipLaunchKernelGGL(p1_partition, dim3(g1), dim3(NTHR), 0, stream,
                       (const int4*)fnp, NP, n_pinb, ent1, cur1);

    const int g2 = 2 * n_pinb;                   // two blocks per pin-bucket
    // d = 0 (x): early-exits when num_slrX <= 1
    hipLaunchKernelGGL(p2_gather, dim3(g2), dim3(NTHR2), 0, stream,
                       ent1, (const float2*)posf, slrx, slry, 0, NP, n_jb, ent2, cur2);
    hipLaunchKernelGGL(p3_compute, dim3(n_jb), dim3(NTHR), 0, stream,
                       ent2, net_weights, inv_gamma, slrx, slry, 0, NP, out);

    // d = 1 (y): second cur2 buffer, no reinit launch needed
    hipLaunchKernelGGL(p2_gather, dim3(g2), dim3(NTHR2), 0, stream,
                       ent1, (const float2*)posf, slrx, slry, 1, NP, n_jb, ent2, cur2 + n_jb);
    hipLaunchKernelGGL(p3_compute, dim3(n_jb), dim3(NTHR), 0, stream,
                       ent2, net_weights, inv_gamma, slrx, slry, 1, NP, out);
}